// Round 2
// baseline (7351.569 us; speedup 1.0000x reference)
//
#include <hip/hip_runtime.h>
#include <hip/hip_bf16.h>

// Problem constants (fixed by reference)
#define N_NODES 50000
#define E_EDGES 800000
#define BN_EPS 1e-5f
#define SLOPE 0.01f

// All float tensors are fp32 (reference is explicitly jnp.float32).
// Integer tensors are int32. Output is fp32[N].

// ---------------------------------------------------------------------------
// K0: x0[n] = concat(emb_deg[deg[n]], emb_lab[lab[n]])  -> [N,128] fp32
// ---------------------------------------------------------------------------
__global__ void k_build_x0(const float* __restrict__ ed, const float* __restrict__ el,
                           const int* __restrict__ nd, const int* __restrict__ nl,
                           float* __restrict__ x0) {
    int idx = blockIdx.x * blockDim.x + threadIdx.x;  // N*64
    if (idx >= N_NODES * 64) return;
    int n = idx >> 6, c = idx & 63;
    x0[(size_t)n * 128 + c]      = ed[nd[n] * 64 + c];
    x0[(size_t)n * 128 + 64 + c] = el[nl[n] * 64 + c];
}

// ---------------------------------------------------------------------------
// K1: agg[dst[e]] += x[src[e]]   (fp32 atomics, thread = edge x 4 cols)
// ---------------------------------------------------------------------------
template<int D>
__global__ void k_scatter(const float* __restrict__ x, const int* __restrict__ src,
                          const int* __restrict__ dst, float* __restrict__ agg) {
    constexpr int CPE = D / 4;  // float4 chunks per edge
    int idx = blockIdx.x * blockDim.x + threadIdx.x;
    if (idx >= E_EDGES * CPE) return;
    int e  = idx / CPE;         // compile-time pow2 -> shift
    int c4 = (idx % CPE) * 4;
    int s = src[e], d = dst[e];
    float4 v = *(const float4*)(x + (size_t)s * D + c4);
    float* a = agg + (size_t)d * D + c4;
    atomicAdd(a + 0, v.x);
    atomicAdd(a + 1, v.y);
    atomicAdd(a + 2, v.z);
    atomicAdd(a + 3, v.w);
}

// ---------------------------------------------------------------------------
// K2: fused GIN MLP:  y = wb @ lrelu(wa @ (x+agg) + ba) + bb, plus BN stats.
// Block = 256 threads = 4 waves, tile = 64 rows. Wave w owns col group w, so
// weight loads are lane-uniform (broadcast). LDS stride D+4 => stride%32==4,
// minimal b128 bank aliasing. lin1 result staged in registers, written back
// into xs (single LDS buffer, fits 64KB static limit).
// ---------------------------------------------------------------------------
template<int D>
__global__ __launch_bounds__(256) void k_mlp(
        const float* __restrict__ x, const float* __restrict__ agg,
        const float* __restrict__ wa, const float* __restrict__ ba,
        const float* __restrict__ wb, const float* __restrict__ bb,
        float* __restrict__ ybuf, float* __restrict__ ssum, float* __restrict__ ssq) {
    constexpr int LDW = D + 4;
    constexpr int JPT = D / 4;   // lin1 cols per thread
    __shared__ float xs[64 * LDW];
    __shared__ float csum[64], csq[64];
    int t = threadIdx.x, r = t & 63, wg = t >> 6;
    int row0 = blockIdx.x * 64, gr = row0 + r;

    // load (x + agg) tile
    for (int i = t; i < 64 * D; i += 256) {
        int rr = i / D, cc = i % D, g = row0 + rr;
        xs[rr * LDW + cc] = (g < N_NODES)
            ? x[(size_t)g * D + cc] + agg[(size_t)g * D + cc] : 0.f;
    }
    __syncthreads();

    // lin1 + lrelu -> registers
    float acc[JPT];
    #pragma unroll
    for (int jj = 0; jj < JPT; ++jj) {
        int j = wg * JPT + jj;
        float a = ba[j];
        const float* wrow = wa + j * D;
        for (int k = 0; k < D; k += 4) {
            float4 xv = *(const float4*)(xs + r * LDW + k);
            float4 wv = *(const float4*)(wrow + k);
            a += xv.x * wv.x + xv.y * wv.y + xv.z * wv.z + xv.w * wv.w;
        }
        acc[jj] = a > 0.f ? a : SLOPE * a;
    }
    __syncthreads();              // all lin1 reads of xs done
    #pragma unroll
    for (int jj = 0; jj < JPT; ++jj) xs[r * LDW + wg * JPT + jj] = acc[jj];
    if (t < 64) { csum[t] = 0.f; csq[t] = 0.f; }
    __syncthreads();              // h tile visible to all waves

    // lin2 (64 out cols; 16 per thread) + BN stats (wave shuffle reduce)
    bool ok = gr < N_NODES;
    #pragma unroll
    for (int jj = 0; jj < 16; ++jj) {
        int j = wg * 16 + jj;
        float a = bb[j];
        const float* wrow = wb + j * D;
        for (int k = 0; k < D; k += 4) {
            float4 xv = *(const float4*)(xs + r * LDW + k);
            float4 wv = *(const float4*)(wrow + k);
            a += xv.x * wv.x + xv.y * wv.y + xv.z * wv.z + xv.w * wv.w;
        }
        if (ok) ybuf[(size_t)gr * 64 + j] = a;
        float s = ok ? a : 0.f, q = s * s;
        #pragma unroll
        for (int o = 32; o; o >>= 1) { s += __shfl_xor(s, o); q += __shfl_xor(q, o); }
        if (r == 0) { atomicAdd(&csum[j], s); atomicAdd(&csq[j], q); }
    }
    __syncthreads();
    if (t < 64) { atomicAdd(&ssum[t], csum[t]); atomicAdd(&ssq[t], csq[t]); }
}

// ---------------------------------------------------------------------------
// K3: BN finalize: scale/shift per column (1 block, 64 threads)
// ---------------------------------------------------------------------------
__global__ void k_bn_fin(const float* __restrict__ ssum, const float* __restrict__ ssq,
                         const float* __restrict__ gw, const float* __restrict__ gb,
                         float* __restrict__ scale, float* __restrict__ shift) {
    int j = threadIdx.x;
    float m = ssum[j] * (1.0f / N_NODES);
    float v = ssq[j] * (1.0f / N_NODES) - m * m;
    float sc = gw[j] * rsqrtf(v + BN_EPS);
    scale[j] = sc;
    shift[j] = gb[j] - m * sc;
}

// ---------------------------------------------------------------------------
// K4: x_out = lrelu(y*scale + shift)
// ---------------------------------------------------------------------------
__global__ void k_bn_apply(const float* __restrict__ y, const float* __restrict__ scale,
                           const float* __restrict__ shift, float* __restrict__ xo) {
    int idx = blockIdx.x * blockDim.x + threadIdx.x;
    if (idx >= N_NODES * 64) return;
    int c = idx & 63;
    float v = y[idx] * scale[c] + shift[c];
    xo[idx] = v > 0.f ? v : SLOPE * v;
}

// ---------------------------------------------------------------------------
// K5: fc1 over the concat [x0|x1|x2|x3] (320 cols) + BN stats
// ---------------------------------------------------------------------------
template<int SD>
__device__ __forceinline__ void fc1_seg(const float* __restrict__ xp, int row0, int t, int r,
                                        int wg, float* xs, const float* __restrict__ w,
                                        int colofs, float acc[16]) {
    __syncthreads();  // previous segment's xs reads done
    for (int i = t; i < 64 * SD; i += 256) {
        int rr = i / SD, cc = i % SD, g = row0 + rr;
        xs[rr * 132 + cc] = (g < N_NODES) ? xp[(size_t)g * SD + cc] : 0.f;
    }
    __syncthreads();
    #pragma unroll
    for (int jj = 0; jj < 16; ++jj) {
        int j = wg * 16 + jj;
        const float* wrow = w + j * 320 + colofs;
        float a = 0.f;
        for (int k = 0; k < SD; k += 4) {
            float4 xv = *(const float4*)(xs + r * 132 + k);
            float4 wv = *(const float4*)(wrow + k);
            a += xv.x * wv.x + xv.y * wv.y + xv.z * wv.z + xv.w * wv.w;
        }
        acc[jj] += a;
    }
}

__global__ __launch_bounds__(256) void k_fc1(
        const float* __restrict__ x0, const float* __restrict__ x1,
        const float* __restrict__ x2, const float* __restrict__ x3,
        const float* __restrict__ w, const float* __restrict__ b,
        float* __restrict__ ybuf, float* __restrict__ ssum, float* __restrict__ ssq) {
    __shared__ float xs[64 * 132];
    __shared__ float csum[64], csq[64];
    int t = threadIdx.x, r = t & 63, wg = t >> 6;
    int row0 = blockIdx.x * 64, gr = row0 + r;
    float acc[16];
    #pragma unroll
    for (int jj = 0; jj < 16; ++jj) acc[jj] = b[wg * 16 + jj];
    fc1_seg<128>(x0, row0, t, r, wg, xs, w, 0,   acc);
    fc1_seg<64> (x1, row0, t, r, wg, xs, w, 128, acc);
    fc1_seg<64> (x2, row0, t, r, wg, xs, w, 192, acc);
    fc1_seg<64> (x3, row0, t, r, wg, xs, w, 256, acc);
    if (t < 64) { csum[t] = 0.f; csq[t] = 0.f; }
    __syncthreads();
    bool ok = gr < N_NODES;
    #pragma unroll
    for (int jj = 0; jj < 16; ++jj) {
        int j = wg * 16 + jj;
        float a = acc[jj];
        if (ok) ybuf[(size_t)gr * 64 + j] = a;
        float s = ok ? a : 0.f, q = s * s;
        #pragma unroll
        for (int o = 32; o; o >>= 1) { s += __shfl_xor(s, o); q += __shfl_xor(q, o); }
        if (r == 0) { atomicAdd(&csum[j], s); atomicAdd(&csq[j], q); }
    }
    __syncthreads();
    if (t < 64) { atomicAdd(&ssum[t], csum[t]); atomicAdd(&ssq[t], csq[t]); }
}

// ---------------------------------------------------------------------------
// K6: out = sigmoid( fc2_w . lrelu(y*scale+shift) + fc2_b )  -> fp32
// ---------------------------------------------------------------------------
__global__ void k_final(const float* __restrict__ y, const float* __restrict__ scale,
                        const float* __restrict__ shift, const float* __restrict__ w2,
                        const float* __restrict__ b2, float* __restrict__ out) {
    __shared__ float sc[64], sh[64], w[64];
    int t = threadIdx.x;
    if (t < 64) { sc[t] = scale[t]; sh[t] = shift[t]; w[t] = w2[t]; }
    __syncthreads();
    int i = blockIdx.x * blockDim.x + t;
    if (i >= N_NODES) return;
    float z = b2[0];
    const float* row = y + (size_t)i * 64;
    #pragma unroll
    for (int c = 0; c < 64; c += 4) {
        float4 v4 = *(const float4*)(row + c);
        float v;
        v = v4.x * sc[c]   + sh[c];   v = v > 0.f ? v : SLOPE * v; z += v * w[c];
        v = v4.y * sc[c+1] + sh[c+1]; v = v > 0.f ? v : SLOPE * v; z += v * w[c+1];
        v = v4.z * sc[c+2] + sh[c+2]; v = v > 0.f ? v : SLOPE * v; z += v * w[c+2];
        v = v4.w * sc[c+3] + sh[c+3]; v = v > 0.f ? v : SLOPE * v; z += v * w[c+3];
    }
    out[i] = 1.f / (1.f + __expf(-z));
}

// ---------------------------------------------------------------------------
extern "C" void kernel_launch(void* const* d_in, const int* in_sizes, int n_in,
                              void* d_out, int out_size, void* d_ws, size_t ws_size,
                              hipStream_t stream) {
    const float* emb_deg = (const float*)d_in[0];
    const float* emb_lab = (const float*)d_in[1];
    const float* wA[3]  = {(const float*)d_in[2],  (const float*)d_in[8],  (const float*)d_in[14]};
    const float* bA[3]  = {(const float*)d_in[3],  (const float*)d_in[9],  (const float*)d_in[15]};
    const float* wB[3]  = {(const float*)d_in[4],  (const float*)d_in[10], (const float*)d_in[16]};
    const float* bB[3]  = {(const float*)d_in[5],  (const float*)d_in[11], (const float*)d_in[17]};
    const float* bnw[3] = {(const float*)d_in[6],  (const float*)d_in[12], (const float*)d_in[18]};
    const float* bnb[3] = {(const float*)d_in[7],  (const float*)d_in[13], (const float*)d_in[19]};
    const float* fc1_w  = (const float*)d_in[20];
    const float* fc1_b  = (const float*)d_in[21];
    const float* fcbn_w = (const float*)d_in[22];
    const float* fcbn_b = (const float*)d_in[23];
    const float* fc2_w  = (const float*)d_in[24];
    const float* fc2_b  = (const float*)d_in[25];
    const int* node_deg = (const int*)d_in[26];
    const int* node_lab = (const int*)d_in[27];
    const int* src = (const int*)d_in[28];
    const int* dst = src + E_EDGES;
    float* out = (float*)d_out;

    // workspace layout (fp32): ~102.4 MB total
    float* ws  = (float*)d_ws;
    float* x0  = ws;                               // N*128
    float* x1  = x0  + (size_t)N_NODES * 128;      // N*64
    float* x2  = x1  + (size_t)N_NODES * 64;       // N*64
    float* x3  = x2  + (size_t)N_NODES * 64;       // N*64
    float* agg = x3  + (size_t)N_NODES * 64;       // N*128 (reused)
    float* ybf = agg + (size_t)N_NODES * 128;      // N*64  (reused)
    float* stat = ybf + (size_t)N_NODES * 64;      // 256 floats
    float* ssum = stat, *ssq = stat + 64, *scale = stat + 128, *shift = stat + 192;

    const int RB = (N_NODES + 63) / 64;  // 782 row-tile blocks

    k_build_x0<<<(N_NODES * 64 + 255) / 256, 256, 0, stream>>>(emb_deg, emb_lab, node_deg, node_lab, x0);

    float* xin[4] = {x0, x1, x2, x3};
    for (int l = 0; l < 3; ++l) {
        int d = (l == 0) ? 128 : 64;
        hipMemsetAsync(agg, 0, (size_t)N_NODES * d * sizeof(float), stream);
        hipMemsetAsync(stat, 0, 128 * sizeof(float), stream);
        if (l == 0) {
            k_scatter<128><<<E_EDGES * 32 / 256, 256, 0, stream>>>(xin[l], src, dst, agg);
            k_mlp<128><<<RB, 256, 0, stream>>>(xin[l], agg, wA[l], bA[l], wB[l], bB[l], ybf, ssum, ssq);
        } else {
            k_scatter<64><<<E_EDGES * 16 / 256, 256, 0, stream>>>(xin[l], src, dst, agg);
            k_mlp<64><<<RB, 256, 0, stream>>>(xin[l], agg, wA[l], bA[l], wB[l], bB[l], ybf, ssum, ssq);
        }
        k_bn_fin<<<1, 64, 0, stream>>>(ssum, ssq, bnw[l], bnb[l], scale, shift);
        k_bn_apply<<<(N_NODES * 64 + 255) / 256, 256, 0, stream>>>(ybf, scale, shift, xin[l + 1]);
    }

    hipMemsetAsync(stat, 0, 128 * sizeof(float), stream);
    k_fc1<<<RB, 256, 0, stream>>>(x0, x1, x2, x3, fc1_w, fc1_b, ybf, ssum, ssq);
    k_bn_fin<<<1, 64, 0, stream>>>(ssum, ssq, fcbn_w, fcbn_b, scale, shift);
    k_final<<<(N_NODES + 255) / 256, 256, 0, stream>>>(ybf, scale, shift, fc2_w, fc2_b, out);
}

// Round 3
// 2385.021 us; speedup vs baseline: 3.0824x; 3.0824x over previous
//
#include <hip/hip_runtime.h>

// Problem constants (fixed by reference)
#define N_NODES 50000
#define E_EDGES 800000
#define BN_EPS 1e-5f
#define SLOPE 0.01f

// All float tensors are fp32; integer tensors int32; output fp32[N].

// ---------------------------------------------------------------------------
// K0: x0[n] = concat(emb_deg[deg[n]], emb_lab[lab[n]])  -> [N,128] fp32
// ---------------------------------------------------------------------------
__global__ void k_build_x0(const float* __restrict__ ed, const float* __restrict__ el,
                           const int* __restrict__ nd, const int* __restrict__ nl,
                           float* __restrict__ x0) {
    int idx = blockIdx.x * blockDim.x + threadIdx.x;  // N*64
    if (idx >= N_NODES * 64) return;
    int n = idx >> 6, c = idx & 63;
    x0[(size_t)n * 128 + c]      = ed[nd[n] * 64 + c];
    x0[(size_t)n * 128 + 64 + c] = el[nl[n] * 64 + c];
}

// ---------------------------------------------------------------------------
// K-cnt: layer-0 aggregation compressed to class counts: 2 atomics/edge
// cnt[d][c] = #src-neighbors of d with deg-class c (c<64) / lab-class c-64
// ---------------------------------------------------------------------------
__global__ void k_cnt(const int* __restrict__ src, const int* __restrict__ dst,
                      const int* __restrict__ nd, const int* __restrict__ nl,
                      float* __restrict__ cnt) {
    int e = blockIdx.x * blockDim.x + threadIdx.x;
    if (e >= E_EDGES) return;
    int s = src[e], d = dst[e];
    atomicAdd(&cnt[(size_t)d * 80 + nd[s]], 1.f);
    atomicAdd(&cnt[(size_t)d * 80 + 64 + nl[s]], 1.f);
}

// ---------------------------------------------------------------------------
// K-expand: agg0[N,128] = cnt @ blockdiag(emb_deg[64,64], emb_lab[16,64])
// block = 64 rows; wave wg owns 32 contiguous output cols (uniform emb reads)
// ---------------------------------------------------------------------------
__global__ __launch_bounds__(256) void k_expand(const float* __restrict__ cnt,
        const float* __restrict__ ed, const float* __restrict__ el,
        float* __restrict__ agg) {
    __shared__ float cs[64 * 81];   // stride 81: 81%32=17 (odd) -> 2-way max
    int t = threadIdx.x;
    int row0 = blockIdx.x * 64;
    for (int i = t; i < 64 * 80; i += 256) {
        int rr = i / 80, cc = i % 80, g = row0 + rr;
        cs[rr * 81 + cc] = (g < N_NODES) ? cnt[(size_t)g * 80 + cc] : 0.f;
    }
    __syncthreads();
    int r = t & 63, wg = t >> 6;
    if (row0 + r >= N_NODES) return;
    float a[32];
    #pragma unroll
    for (int q = 0; q < 32; ++q) a[q] = 0.f;
    if (wg < 2) {
        const float* eb = ed + wg * 32;
        #pragma unroll 1
        for (int c = 0; c < 64; ++c) {
            float cv = cs[r * 81 + c];
            const float* er = eb + c * 64;
            #pragma unroll
            for (int q = 0; q < 32; ++q) a[q] += cv * er[q];
        }
    } else {
        const float* eb = el + (wg - 2) * 32;
        #pragma unroll 1
        for (int c = 0; c < 16; ++c) {
            float cv = cs[r * 81 + 64 + c];
            const float* er = eb + c * 64;
            #pragma unroll
            for (int q = 0; q < 32; ++q) a[q] += cv * er[q];
        }
    }
    float* op = agg + (size_t)(row0 + r) * 128 + wg * 32;
    #pragma unroll
    for (int q = 0; q < 32; q += 4)
        *(float4*)(op + q) = make_float4(a[q], a[q + 1], a[q + 2], a[q + 3]);
}

// ---------------------------------------------------------------------------
// K1: agg[dst[e]] += x[src[e]]  (layers 1,2; D=64; fp32 atomics)
// ---------------------------------------------------------------------------
template<int D>
__global__ void k_scatter(const float* __restrict__ x, const int* __restrict__ src,
                          const int* __restrict__ dst, float* __restrict__ agg) {
    constexpr int CPE = D / 4;
    int idx = blockIdx.x * blockDim.x + threadIdx.x;
    if (idx >= E_EDGES * CPE) return;
    int e  = idx / CPE;
    int c4 = (idx % CPE) * 4;
    int s = src[e], d = dst[e];
    float4 v = *(const float4*)(x + (size_t)s * D + c4);
    float* a = agg + (size_t)d * D + c4;
    atomicAdd(a + 0, v.x);
    atomicAdd(a + 1, v.y);
    atomicAdd(a + 2, v.z);
    atomicAdd(a + 3, v.w);
}

// ---------------------------------------------------------------------------
// dot of 8 float4 (32 K-elements), two partial chains for latency
// ---------------------------------------------------------------------------
__device__ __forceinline__ float dot32(const float4 xv[8], const float4* __restrict__ wr) {
    float p0 = 0.f, p1 = 0.f;
    #pragma unroll
    for (int q = 0; q < 8; q += 2) {
        float4 w0 = wr[q], w1 = wr[q + 1];
        p0 += xv[q].x * w0.x + xv[q].y * w0.y + xv[q].z * w0.z + xv[q].w * w0.w;
        p1 += xv[q + 1].x * w1.x + xv[q + 1].y * w1.y + xv[q + 1].z * w1.z + xv[q + 1].w * w1.w;
    }
    return p0 + p1;
}

// ---------------------------------------------------------------------------
// K2: fused GIN MLP. Spill-safe: K cached in 8xfloat4 regs per 32-segment,
// output cols processed in chunks of 8 (acc[] fully unrolled, ~100 VGPR).
// ---------------------------------------------------------------------------
template<int D>
__global__ __launch_bounds__(256) void k_mlp(
        const float* __restrict__ x, const float* __restrict__ agg,
        const float* __restrict__ wa, const float* __restrict__ ba,
        const float* __restrict__ wb, const float* __restrict__ bb,
        float* __restrict__ ybuf, float* __restrict__ ssum, float* __restrict__ ssq) {
    constexpr int LDW = D + 4;
    constexpr int JPT = D / 4;   // lin1 cols per thread
    __shared__ float xs[64 * LDW];
    __shared__ float csum[64], csq[64];
    int t = threadIdx.x, r = t & 63, wg = t >> 6;
    int row0 = blockIdx.x * 64, gr = row0 + r;

    for (int i = t; i < 64 * D; i += 256) {
        int rr = i / D, cc = i % D, g = row0 + rr;
        xs[rr * LDW + cc] = (g < N_NODES)
            ? x[(size_t)g * D + cc] + agg[(size_t)g * D + cc] : 0.f;
    }
    __syncthreads();

    // ---- lin1 + lrelu -> h registers (JPT = 16 or 32, const-indexed)
    float h[JPT];
    #pragma unroll
    for (int jc = 0; jc < JPT; jc += 8) {
        float acc[8];
        #pragma unroll
        for (int jj = 0; jj < 8; ++jj) acc[jj] = ba[wg * JPT + jc + jj];
        #pragma unroll 1
        for (int ks = 0; ks < D; ks += 32) {
            float4 xv[8];
            #pragma unroll
            for (int q = 0; q < 8; ++q)
                xv[q] = *(const float4*)(xs + r * LDW + ks + 4 * q);
            #pragma unroll
            for (int jj = 0; jj < 8; ++jj) {
                const float4* wr = (const float4*)(wa + (size_t)(wg * JPT + jc + jj) * D + ks);
                acc[jj] += dot32(xv, wr);
            }
        }
        #pragma unroll
        for (int jj = 0; jj < 8; ++jj) {
            float a = acc[jj];
            h[jc + jj] = a > 0.f ? a : SLOPE * a;
        }
    }
    __syncthreads();              // all lin1 reads of xs done
    #pragma unroll
    for (int jj = 0; jj < JPT; ++jj) xs[r * LDW + wg * JPT + jj] = h[jj];
    if (t < 64) { csum[t] = 0.f; csq[t] = 0.f; }
    __syncthreads();              // h tile visible

    // ---- lin2 (64 cols; 16/thread in 2 chunks) + BN stats
    bool ok = gr < N_NODES;
    #pragma unroll
    for (int jc = 0; jc < 16; jc += 8) {
        float acc[8];
        #pragma unroll
        for (int jj = 0; jj < 8; ++jj) acc[jj] = bb[wg * 16 + jc + jj];
        #pragma unroll 1
        for (int ks = 0; ks < D; ks += 32) {
            float4 xv[8];
            #pragma unroll
            for (int q = 0; q < 8; ++q)
                xv[q] = *(const float4*)(xs + r * LDW + ks + 4 * q);
            #pragma unroll
            for (int jj = 0; jj < 8; ++jj) {
                const float4* wr = (const float4*)(wb + (size_t)(wg * 16 + jc + jj) * D + ks);
                acc[jj] += dot32(xv, wr);
            }
        }
        #pragma unroll
        for (int jj = 0; jj < 8; ++jj) {
            int j = wg * 16 + jc + jj;
            float a = acc[jj];
            if (ok) ybuf[(size_t)gr * 64 + j] = a;
            float s = ok ? a : 0.f, q = s * s;
            #pragma unroll
            for (int o = 32; o; o >>= 1) { s += __shfl_xor(s, o); q += __shfl_xor(q, o); }
            if (r == 0) { atomicAdd(&csum[j], s); atomicAdd(&csq[j], q); }
        }
    }
    __syncthreads();
    if (t < 64) { atomicAdd(&ssum[t], csum[t]); atomicAdd(&ssq[t], csq[t]); }
}

// ---------------------------------------------------------------------------
// K3: BN finalize
// ---------------------------------------------------------------------------
__global__ void k_bn_fin(const float* __restrict__ ssum, const float* __restrict__ ssq,
                         const float* __restrict__ gw, const float* __restrict__ gb,
                         float* __restrict__ scale, float* __restrict__ shift) {
    int j = threadIdx.x;
    float m = ssum[j] * (1.0f / N_NODES);
    float v = ssq[j] * (1.0f / N_NODES) - m * m;
    float sc = gw[j] * rsqrtf(v + BN_EPS);
    scale[j] = sc;
    shift[j] = gb[j] - m * sc;
}

// ---------------------------------------------------------------------------
// K4: x_out = lrelu(y*scale + shift)
// ---------------------------------------------------------------------------
__global__ void k_bn_apply(const float* __restrict__ y, const float* __restrict__ scale,
                           const float* __restrict__ shift, float* __restrict__ xo) {
    int idx = blockIdx.x * blockDim.x + threadIdx.x;
    if (idx >= N_NODES * 64) return;
    int c = idx & 63;
    float v = y[idx] * scale[c] + shift[c];
    xo[idx] = v > 0.f ? v : SLOPE * v;
}

// ---------------------------------------------------------------------------
// K5: fc1 over concat [x0|x1|x2|x3] (K=320) + BN stats. Same spill-safe form.
// ---------------------------------------------------------------------------
template<int SD>
__device__ __forceinline__ void fc1_seg(const float* __restrict__ xp, int row0, int t, int r,
                                        int wg, float* xs, const float* __restrict__ w,
                                        int colofs, float acc[16]) {
    constexpr int LDW = SD + 4;
    __syncthreads();  // previous segment's xs reads done
    for (int i = t; i < 64 * SD; i += 256) {
        int rr = i / SD, cc = i % SD, g = row0 + rr;
        xs[rr * LDW + cc] = (g < N_NODES) ? xp[(size_t)g * SD + cc] : 0.f;
    }
    __syncthreads();
    #pragma unroll 1
    for (int ks = 0; ks < SD; ks += 32) {
        float4 xv[8];
        #pragma unroll
        for (int q = 0; q < 8; ++q)
            xv[q] = *(const float4*)(xs + r * LDW + ks + 4 * q);
        #pragma unroll
        for (int jj = 0; jj < 16; ++jj) {
            const float4* wr = (const float4*)(w + (size_t)(wg * 16 + jj) * 320 + colofs + ks);
            acc[jj] += dot32(xv, wr);
        }
    }
}

__global__ __launch_bounds__(256) void k_fc1(
        const float* __restrict__ x0, const float* __restrict__ x1,
        const float* __restrict__ x2, const float* __restrict__ x3,
        const float* __restrict__ w, const float* __restrict__ b,
        float* __restrict__ ybuf, float* __restrict__ ssum, float* __restrict__ ssq) {
    __shared__ float xs[64 * 132];
    __shared__ float csum[64], csq[64];
    int t = threadIdx.x, r = t & 63, wg = t >> 6;
    int row0 = blockIdx.x * 64, gr = row0 + r;
    float acc[16];
    #pragma unroll
    for (int jj = 0; jj < 16; ++jj) acc[jj] = b[wg * 16 + jj];
    fc1_seg<128>(x0, row0, t, r, wg, xs, w, 0,   acc);
    fc1_seg<64> (x1, row0, t, r, wg, xs, w, 128, acc);
    fc1_seg<64> (x2, row0, t, r, wg, xs, w, 192, acc);
    fc1_seg<64> (x3, row0, t, r, wg, xs, w, 256, acc);
    if (t < 64) { csum[t] = 0.f; csq[t] = 0.f; }
    __syncthreads();
    bool ok = gr < N_NODES;
    #pragma unroll
    for (int jj = 0; jj < 16; ++jj) {
        int j = wg * 16 + jj;
        float a = acc[jj];
        if (ok) ybuf[(size_t)gr * 64 + j] = a;
        float s = ok ? a : 0.f, q = s * s;
        #pragma unroll
        for (int o = 32; o; o >>= 1) { s += __shfl_xor(s, o); q += __shfl_xor(q, o); }
        if (r == 0) { atomicAdd(&csum[j], s); atomicAdd(&csq[j], q); }
    }
    __syncthreads();
    if (t < 64) { atomicAdd(&ssum[t], csum[t]); atomicAdd(&ssq[t], csq[t]); }
}

// ---------------------------------------------------------------------------
// K6: out = sigmoid( fc2_w . lrelu(y*scale+shift) + fc2_b )
// ---------------------------------------------------------------------------
__global__ void k_final(const float* __restrict__ y, const float* __restrict__ scale,
                        const float* __restrict__ shift, const float* __restrict__ w2,
                        const float* __restrict__ b2, float* __restrict__ out) {
    __shared__ float sc[64], sh[64], w[64];
    int t = threadIdx.x;
    if (t < 64) { sc[t] = scale[t]; sh[t] = shift[t]; w[t] = w2[t]; }
    __syncthreads();
    int i = blockIdx.x * blockDim.x + t;
    if (i >= N_NODES) return;
    float z = b2[0];
    const float* row = y + (size_t)i * 64;
    #pragma unroll
    for (int c = 0; c < 64; c += 4) {
        float4 v4 = *(const float4*)(row + c);
        float v;
        v = v4.x * sc[c]   + sh[c];   v = v > 0.f ? v : SLOPE * v; z += v * w[c];
        v = v4.y * sc[c+1] + sh[c+1]; v = v > 0.f ? v : SLOPE * v; z += v * w[c+1];
        v = v4.z * sc[c+2] + sh[c+2]; v = v > 0.f ? v : SLOPE * v; z += v * w[c+2];
        v = v4.w * sc[c+3] + sh[c+3]; v = v > 0.f ? v : SLOPE * v; z += v * w[c+3];
    }
    out[i] = 1.f / (1.f + __expf(-z));
}

// ---------------------------------------------------------------------------
extern "C" void kernel_launch(void* const* d_in, const int* in_sizes, int n_in,
                              void* d_out, int out_size, void* d_ws, size_t ws_size,
                              hipStream_t stream) {
    const float* emb_deg = (const float*)d_in[0];
    const float* emb_lab = (const float*)d_in[1];
    const float* wA[3]  = {(const float*)d_in[2],  (const float*)d_in[8],  (const float*)d_in[14]};
    const float* bA[3]  = {(const float*)d_in[3],  (const float*)d_in[9],  (const float*)d_in[15]};
    const float* wB[3]  = {(const float*)d_in[4],  (const float*)d_in[10], (const float*)d_in[16]};
    const float* bB[3]  = {(const float*)d_in[5],  (const float*)d_in[11], (const float*)d_in[17]};
    const float* bnw[3] = {(const float*)d_in[6],  (const float*)d_in[12], (const float*)d_in[18]};
    const float* bnb[3] = {(const float*)d_in[7],  (const float*)d_in[13], (const float*)d_in[19]};
    const float* fc1_w  = (const float*)d_in[20];
    const float* fc1_b  = (const float*)d_in[21];
    const float* fcbn_w = (const float*)d_in[22];
    const float* fcbn_b = (const float*)d_in[23];
    const float* fc2_w  = (const float*)d_in[24];
    const float* fc2_b  = (const float*)d_in[25];
    const int* node_deg = (const int*)d_in[26];
    const int* node_lab = (const int*)d_in[27];
    const int* src = (const int*)d_in[28];
    const int* dst = src + E_EDGES;
    float* out = (float*)d_out;

    // workspace layout (fp32)
    float* ws  = (float*)d_ws;
    float* x0  = ws;                               // N*128
    float* x1  = x0  + (size_t)N_NODES * 128;      // N*64
    float* x2  = x1  + (size_t)N_NODES * 64;       // N*64
    float* x3  = x2  + (size_t)N_NODES * 64;       // N*64
    float* agg = x3  + (size_t)N_NODES * 64;       // N*128 (reused)
    float* ybf = agg + (size_t)N_NODES * 128;      // N*64  (reused)
    float* stat = ybf + (size_t)N_NODES * 64;      // 256 floats
    float* ssum = stat, *ssq = stat + 64, *scale = stat + 128, *shift = stat + 192;
    // cnt[N,80] borrows x2+x3 (dead until layer-1 bn_apply writes x2)
    float* cnt = x2;

    const int RB = (N_NODES + 63) / 64;  // 782 row-tile blocks

    k_build_x0<<<(N_NODES * 64 + 255) / 256, 256, 0, stream>>>(emb_deg, emb_lab, node_deg, node_lab, x0);

    // ---- layer 0: compressed aggregation
    hipMemsetAsync(cnt, 0, (size_t)N_NODES * 80 * sizeof(float), stream);
    k_cnt<<<(E_EDGES + 255) / 256, 256, 0, stream>>>(src, dst, node_deg, node_lab, cnt);
    k_expand<<<RB, 256, 0, stream>>>(cnt, emb_deg, emb_lab, agg);
    hipMemsetAsync(stat, 0, 128 * sizeof(float), stream);
    k_mlp<128><<<RB, 256, 0, stream>>>(x0, agg, wA[0], bA[0], wB[0], bB[0], ybf, ssum, ssq);
    k_bn_fin<<<1, 64, 0, stream>>>(ssum, ssq, bnw[0], bnb[0], scale, shift);
    k_bn_apply<<<(N_NODES * 64 + 255) / 256, 256, 0, stream>>>(ybf, scale, shift, x1);

    // ---- layers 1,2: feature scatter + MLP
    float* xin[4] = {x0, x1, x2, x3};
    for (int l = 1; l < 3; ++l) {
        hipMemsetAsync(agg, 0, (size_t)N_NODES * 64 * sizeof(float), stream);
        hipMemsetAsync(stat, 0, 128 * sizeof(float), stream);
        k_scatter<64><<<E_EDGES * 16 / 256, 256, 0, stream>>>(xin[l], src, dst, agg);
        k_mlp<64><<<RB, 256, 0, stream>>>(xin[l], agg, wA[l], bA[l], wB[l], bB[l], ybf, ssum, ssq);
        k_bn_fin<<<1, 64, 0, stream>>>(ssum, ssq, bnw[l], bnb[l], scale, shift);
        k_bn_apply<<<(N_NODES * 64 + 255) / 256, 256, 0, stream>>>(ybf, scale, shift, xin[l + 1]);
    }

    hipMemsetAsync(stat, 0, 128 * sizeof(float), stream);
    k_fc1<<<RB, 256, 0, stream>>>(x0, x1, x2, x3, fc1_w, fc1_b, ybf, ssum, ssq);
    k_bn_fin<<<1, 64, 0, stream>>>(ssum, ssq, fcbn_w, fcbn_b, scale, shift);
    k_final<<<(N_NODES + 255) / 256, 256, 0, stream>>>(ybf, scale, shift, fc2_w, fc2_b, out);
}

// Round 4
// 1235.398 us; speedup vs baseline: 5.9508x; 1.9306x over previous
//
#include <hip/hip_runtime.h>

// Problem constants (fixed by reference)
#define N_NODES 50000
#define E_EDGES 800000
#define BN_EPS 1e-5f
#define SLOPE 0.01f

// All float tensors are fp32; integer tensors int32; output fp32[N].

// ---------------------------------------------------------------------------
// K0: x0[n] = concat(emb_deg[deg[n]], emb_lab[lab[n]])  -> [N,128] fp32
// ---------------------------------------------------------------------------
__global__ void k_build_x0(const float* __restrict__ ed, const float* __restrict__ el,
                           const int* __restrict__ nd, const int* __restrict__ nl,
                           float* __restrict__ x0) {
    int idx = blockIdx.x * blockDim.x + threadIdx.x;  // N*64
    if (idx >= N_NODES * 64) return;
    int n = idx >> 6, c = idx & 63;
    x0[(size_t)n * 128 + c]      = ed[nd[n] * 64 + c];
    x0[(size_t)n * 128 + 64 + c] = el[nl[n] * 64 + c];
}

// ---------------------------------------------------------------------------
// CSR build: degree histogram -> exclusive scan -> bucket fill
// ---------------------------------------------------------------------------
__global__ void k_deg(const int* __restrict__ dst, int* __restrict__ deg) {
    int e = blockIdx.x * blockDim.x + threadIdx.x;
    if (e >= E_EDGES) return;
    atomicAdd(&deg[dst[e]], 1);
}

__global__ __launch_bounds__(1024) void k_scan(const int* __restrict__ deg,
        int* __restrict__ rowptr, int* __restrict__ wptr) {
    __shared__ int part[1024];
    int t = threadIdx.x;
    const int PER = (N_NODES + 1023) / 1024;  // 49
    int base = t * PER;
    int s = 0;
    for (int i = 0; i < PER; ++i) {
        int idx = base + i;
        if (idx < N_NODES) s += deg[idx];
    }
    part[t] = s;
    __syncthreads();
    // Hillis-Steele inclusive scan over 1024 partials
    for (int off = 1; off < 1024; off <<= 1) {
        int v = (t >= off) ? part[t - off] : 0;
        __syncthreads();
        part[t] += v;
        __syncthreads();
    }
    int run = (t == 0) ? 0 : part[t - 1];
    for (int i = 0; i < PER; ++i) {
        int idx = base + i;
        if (idx < N_NODES) {
            rowptr[idx] = run;
            wptr[idx]   = run;
            run += deg[idx];
        }
    }
}

__global__ void k_fill(const int* __restrict__ src, const int* __restrict__ dst,
                       int* __restrict__ wptr, int* __restrict__ eid) {
    int e = blockIdx.x * blockDim.x + threadIdx.x;
    if (e >= E_EDGES) return;
    int pos = atomicAdd(&wptr[dst[e]], 1);
    eid[pos] = src[e];
}

// ---------------------------------------------------------------------------
// Gather: one wave per dst node, lane = column. Zero atomics.
// ---------------------------------------------------------------------------
__global__ __launch_bounds__(256) void k_gather64(const float* __restrict__ x,
        const int* __restrict__ rowptr, const int* __restrict__ deg,
        const int* __restrict__ eid, float* __restrict__ agg) {
    int gid = blockIdx.x * blockDim.x + threadIdx.x;
    int node = gid >> 6, lane = gid & 63;
    if (node >= N_NODES) return;
    int start = rowptr[node], n = deg[node];
    float a0 = 0.f, a1 = 0.f;
    int i = 0;
    for (; i + 2 <= n; i += 2) {
        int s0 = eid[start + i], s1 = eid[start + i + 1];
        a0 += x[(size_t)s0 * 64 + lane];
        a1 += x[(size_t)s1 * 64 + lane];
    }
    if (i < n) a0 += x[(size_t)eid[start + i] * 64 + lane];
    agg[(size_t)node * 64 + lane] = a0 + a1;
}

__global__ __launch_bounds__(256) void k_gather128(const float* __restrict__ x,
        const int* __restrict__ rowptr, const int* __restrict__ deg,
        const int* __restrict__ eid, float* __restrict__ agg) {
    int gid = blockIdx.x * blockDim.x + threadIdx.x;
    int node = gid >> 6, lane = gid & 63;
    if (node >= N_NODES) return;
    int start = rowptr[node], n = deg[node];
    float ax0 = 0.f, ay0 = 0.f, ax1 = 0.f, ay1 = 0.f;
    int i = 0;
    for (; i + 2 <= n; i += 2) {
        int s0 = eid[start + i], s1 = eid[start + i + 1];
        float2 v0 = *(const float2*)(x + (size_t)s0 * 128 + lane * 2);
        float2 v1 = *(const float2*)(x + (size_t)s1 * 128 + lane * 2);
        ax0 += v0.x; ay0 += v0.y; ax1 += v1.x; ay1 += v1.y;
    }
    if (i < n) {
        float2 v = *(const float2*)(x + (size_t)eid[start + i] * 128 + lane * 2);
        ax0 += v.x; ay0 += v.y;
    }
    *(float2*)(agg + (size_t)node * 128 + lane * 2) = make_float2(ax0 + ax1, ay0 + ay1);
}

// ---------------------------------------------------------------------------
// dot of 8 float4 (32 K-elements), two partial chains for latency
// ---------------------------------------------------------------------------
__device__ __forceinline__ float dot32(const float4 xv[8], const float4* __restrict__ wr) {
    float p0 = 0.f, p1 = 0.f;
    #pragma unroll
    for (int q = 0; q < 8; q += 2) {
        float4 w0 = wr[q], w1 = wr[q + 1];
        p0 += xv[q].x * w0.x + xv[q].y * w0.y + xv[q].z * w0.z + xv[q].w * w0.w;
        p1 += xv[q + 1].x * w1.x + xv[q + 1].y * w1.y + xv[q + 1].z * w1.z + xv[q + 1].w * w1.w;
    }
    return p0 + p1;
}

// ---------------------------------------------------------------------------
// K2: fused GIN MLP. Spill-safe: K cached in 8xfloat4 regs per 32-segment,
// output cols processed in chunks of 8 (acc[] fully unrolled, ~100 VGPR).
// ---------------------------------------------------------------------------
template<int D>
__global__ __launch_bounds__(256) void k_mlp(
        const float* __restrict__ x, const float* __restrict__ agg,
        const float* __restrict__ wa, const float* __restrict__ ba,
        const float* __restrict__ wb, const float* __restrict__ bb,
        float* __restrict__ ybuf, float* __restrict__ ssum, float* __restrict__ ssq) {
    constexpr int LDW = D + 4;
    constexpr int JPT = D / 4;   // lin1 cols per thread
    __shared__ float xs[64 * LDW];
    __shared__ float csum[64], csq[64];
    int t = threadIdx.x, r = t & 63, wg = t >> 6;
    int row0 = blockIdx.x * 64, gr = row0 + r;

    for (int i = t; i < 64 * D; i += 256) {
        int rr = i / D, cc = i % D, g = row0 + rr;
        xs[rr * LDW + cc] = (g < N_NODES)
            ? x[(size_t)g * D + cc] + agg[(size_t)g * D + cc] : 0.f;
    }
    __syncthreads();

    // ---- lin1 + lrelu -> h registers
    float h[JPT];
    #pragma unroll
    for (int jc = 0; jc < JPT; jc += 8) {
        float acc[8];
        #pragma unroll
        for (int jj = 0; jj < 8; ++jj) acc[jj] = ba[wg * JPT + jc + jj];
        #pragma unroll 1
        for (int ks = 0; ks < D; ks += 32) {
            float4 xv[8];
            #pragma unroll
            for (int q = 0; q < 8; ++q)
                xv[q] = *(const float4*)(xs + r * LDW + ks + 4 * q);
            #pragma unroll
            for (int jj = 0; jj < 8; ++jj) {
                const float4* wr = (const float4*)(wa + (size_t)(wg * JPT + jc + jj) * D + ks);
                acc[jj] += dot32(xv, wr);
            }
        }
        #pragma unroll
        for (int jj = 0; jj < 8; ++jj) {
            float a = acc[jj];
            h[jc + jj] = a > 0.f ? a : SLOPE * a;
        }
    }
    __syncthreads();              // all lin1 reads of xs done
    #pragma unroll
    for (int jj = 0; jj < JPT; ++jj) xs[r * LDW + wg * JPT + jj] = h[jj];
    if (t < 64) { csum[t] = 0.f; csq[t] = 0.f; }
    __syncthreads();              // h tile visible

    // ---- lin2 (64 cols; 16/thread in 2 chunks) + BN stats
    bool ok = gr < N_NODES;
    #pragma unroll
    for (int jc = 0; jc < 16; jc += 8) {
        float acc[8];
        #pragma unroll
        for (int jj = 0; jj < 8; ++jj) acc[jj] = bb[wg * 16 + jc + jj];
        #pragma unroll 1
        for (int ks = 0; ks < D; ks += 32) {
            float4 xv[8];
            #pragma unroll
            for (int q = 0; q < 8; ++q)
                xv[q] = *(const float4*)(xs + r * LDW + ks + 4 * q);
            #pragma unroll
            for (int jj = 0; jj < 8; ++jj) {
                const float4* wr = (const float4*)(wb + (size_t)(wg * 16 + jc + jj) * D + ks);
                acc[jj] += dot32(xv, wr);
            }
        }
        #pragma unroll
        for (int jj = 0; jj < 8; ++jj) {
            int j = wg * 16 + jc + jj;
            float a = acc[jj];
            if (ok) ybuf[(size_t)gr * 64 + j] = a;
            float s = ok ? a : 0.f, q = s * s;
            #pragma unroll
            for (int o = 32; o; o >>= 1) { s += __shfl_xor(s, o); q += __shfl_xor(q, o); }
            if (r == 0) { atomicAdd(&csum[j], s); atomicAdd(&csq[j], q); }
        }
    }
    __syncthreads();
    if (t < 64) { atomicAdd(&ssum[t], csum[t]); atomicAdd(&ssq[t], csq[t]); }
}

// ---------------------------------------------------------------------------
// K3: BN finalize
// ---------------------------------------------------------------------------
__global__ void k_bn_fin(const float* __restrict__ ssum, const float* __restrict__ ssq,
                         const float* __restrict__ gw, const float* __restrict__ gb,
                         float* __restrict__ scale, float* __restrict__ shift) {
    int j = threadIdx.x;
    float m = ssum[j] * (1.0f / N_NODES);
    float v = ssq[j] * (1.0f / N_NODES) - m * m;
    float sc = gw[j] * rsqrtf(v + BN_EPS);
    scale[j] = sc;
    shift[j] = gb[j] - m * sc;
}

// ---------------------------------------------------------------------------
// K4: x_out = lrelu(y*scale + shift)
// ---------------------------------------------------------------------------
__global__ void k_bn_apply(const float* __restrict__ y, const float* __restrict__ scale,
                           const float* __restrict__ shift, float* __restrict__ xo) {
    int idx = blockIdx.x * blockDim.x + threadIdx.x;
    if (idx >= N_NODES * 64) return;
    int c = idx & 63;
    float v = y[idx] * scale[c] + shift[c];
    xo[idx] = v > 0.f ? v : SLOPE * v;
}

// ---------------------------------------------------------------------------
// K5: fc1 over concat [x0|x1|x2|x3] (K=320) + BN stats
// ---------------------------------------------------------------------------
template<int SD>
__device__ __forceinline__ void fc1_seg(const float* __restrict__ xp, int row0, int t, int r,
                                        int wg, float* xs, const float* __restrict__ w,
                                        int colofs, float acc[16]) {
    constexpr int LDW = SD + 4;
    __syncthreads();  // previous segment's xs reads done
    for (int i = t; i < 64 * SD; i += 256) {
        int rr = i / SD, cc = i % SD, g = row0 + rr;
        xs[rr * LDW + cc] = (g < N_NODES) ? xp[(size_t)g * SD + cc] : 0.f;
    }
    __syncthreads();
    #pragma unroll 1
    for (int ks = 0; ks < SD; ks += 32) {
        float4 xv[8];
        #pragma unroll
        for (int q = 0; q < 8; ++q)
            xv[q] = *(const float4*)(xs + r * LDW + ks + 4 * q);
        #pragma unroll
        for (int jj = 0; jj < 16; ++jj) {
            const float4* wr = (const float4*)(w + (size_t)(wg * 16 + jj) * 320 + colofs + ks);
            acc[jj] += dot32(xv, wr);
        }
    }
}

__global__ __launch_bounds__(256) void k_fc1(
        const float* __restrict__ x0, const float* __restrict__ x1,
        const float* __restrict__ x2, const float* __restrict__ x3,
        const float* __restrict__ w, const float* __restrict__ b,
        float* __restrict__ ybuf, float* __restrict__ ssum, float* __restrict__ ssq) {
    __shared__ float xs[64 * 132];
    __shared__ float csum[64], csq[64];
    int t = threadIdx.x, r = t & 63, wg = t >> 6;
    int row0 = blockIdx.x * 64, gr = row0 + r;
    float acc[16];
    #pragma unroll
    for (int jj = 0; jj < 16; ++jj) acc[jj] = b[wg * 16 + jj];
    fc1_seg<128>(x0, row0, t, r, wg, xs, w, 0,   acc);
    fc1_seg<64> (x1, row0, t, r, wg, xs, w, 128, acc);
    fc1_seg<64> (x2, row0, t, r, wg, xs, w, 192, acc);
    fc1_seg<64> (x3, row0, t, r, wg, xs, w, 256, acc);
    if (t < 64) { csum[t] = 0.f; csq[t] = 0.f; }
    __syncthreads();
    bool ok = gr < N_NODES;
    #pragma unroll
    for (int jj = 0; jj < 16; ++jj) {
        int j = wg * 16 + jj;
        float a = acc[jj];
        if (ok) ybuf[(size_t)gr * 64 + j] = a;
        float s = ok ? a : 0.f, q = s * s;
        #pragma unroll
        for (int o = 32; o; o >>= 1) { s += __shfl_xor(s, o); q += __shfl_xor(q, o); }
        if (r == 0) { atomicAdd(&csum[j], s); atomicAdd(&csq[j], q); }
    }
    __syncthreads();
    if (t < 64) { atomicAdd(&ssum[t], csum[t]); atomicAdd(&ssq[t], csq[t]); }
}

// ---------------------------------------------------------------------------
// K6: out = sigmoid( fc2_w . lrelu(y*scale+shift) + fc2_b )
// ---------------------------------------------------------------------------
__global__ void k_final(const float* __restrict__ y, const float* __restrict__ scale,
                        const float* __restrict__ shift, const float* __restrict__ w2,
                        const float* __restrict__ b2, float* __restrict__ out) {
    __shared__ float sc[64], sh[64], w[64];
    int t = threadIdx.x;
    if (t < 64) { sc[t] = scale[t]; sh[t] = shift[t]; w[t] = w2[t]; }
    __syncthreads();
    int i = blockIdx.x * blockDim.x + t;
    if (i >= N_NODES) return;
    float z = b2[0];
    const float* row = y + (size_t)i * 64;
    #pragma unroll
    for (int c = 0; c < 64; c += 4) {
        float4 v4 = *(const float4*)(row + c);
        float v;
        v = v4.x * sc[c]   + sh[c];   v = v > 0.f ? v : SLOPE * v; z += v * w[c];
        v = v4.y * sc[c+1] + sh[c+1]; v = v > 0.f ? v : SLOPE * v; z += v * w[c+1];
        v = v4.z * sc[c+2] + sh[c+2]; v = v > 0.f ? v : SLOPE * v; z += v * w[c+2];
        v = v4.w * sc[c+3] + sh[c+3]; v = v > 0.f ? v : SLOPE * v; z += v * w[c+3];
    }
    out[i] = 1.f / (1.f + __expf(-z));
}

// ---------------------------------------------------------------------------
extern "C" void kernel_launch(void* const* d_in, const int* in_sizes, int n_in,
                              void* d_out, int out_size, void* d_ws, size_t ws_size,
                              hipStream_t stream) {
    const float* emb_deg = (const float*)d_in[0];
    const float* emb_lab = (const float*)d_in[1];
    const float* wA[3]  = {(const float*)d_in[2],  (const float*)d_in[8],  (const float*)d_in[14]};
    const float* bA[3]  = {(const float*)d_in[3],  (const float*)d_in[9],  (const float*)d_in[15]};
    const float* wB[3]  = {(const float*)d_in[4],  (const float*)d_in[10], (const float*)d_in[16]};
    const float* bB[3]  = {(const float*)d_in[5],  (const float*)d_in[11], (const float*)d_in[17]};
    const float* bnw[3] = {(const float*)d_in[6],  (const float*)d_in[12], (const float*)d_in[18]};
    const float* bnb[3] = {(const float*)d_in[7],  (const float*)d_in[13], (const float*)d_in[19]};
    const float* fc1_w  = (const float*)d_in[20];
    const float* fc1_b  = (const float*)d_in[21];
    const float* fcbn_w = (const float*)d_in[22];
    const float* fcbn_b = (const float*)d_in[23];
    const float* fc2_w  = (const float*)d_in[24];
    const float* fc2_b  = (const float*)d_in[25];
    const int* node_deg = (const int*)d_in[26];
    const int* node_lab = (const int*)d_in[27];
    const int* src = (const int*)d_in[28];
    const int* dst = src + E_EDGES;
    float* out = (float*)d_out;

    // workspace layout
    float* ws  = (float*)d_ws;
    float* x0  = ws;                               // N*128
    float* x1  = x0  + (size_t)N_NODES * 128;      // N*64
    float* x2  = x1  + (size_t)N_NODES * 64;       // N*64
    float* x3  = x2  + (size_t)N_NODES * 64;       // N*64
    float* agg = x3  + (size_t)N_NODES * 64;       // N*128
    float* ybf = agg + (size_t)N_NODES * 128;      // N*64
    float* stat = ybf + (size_t)N_NODES * 64;      // 256 floats
    float* ssum = stat, *ssq = stat + 64, *scale = stat + 128, *shift = stat + 192;
    // CSR arrays (int) after stat
    int* deg    = (int*)(stat + 256);              // N
    int* rowptr = deg + N_NODES;                   // N
    int* wptr   = rowptr + N_NODES;                // N
    int* eid    = wptr + N_NODES;                  // E

    const int RB = (N_NODES + 63) / 64;            // 782 row-tile blocks
    const int GB = (N_NODES * 64 + 255) / 256;     // 12500 gather blocks
    const int EB = (E_EDGES + 255) / 256;          // 3125 edge blocks

    k_build_x0<<<GB, 256, 0, stream>>>(emb_deg, emb_lab, node_deg, node_lab, x0);

    // ---- CSR build (per launch; identical work every call)
    hipMemsetAsync(deg, 0, N_NODES * sizeof(int), stream);
    k_deg<<<EB, 256, 0, stream>>>(dst, deg);
    k_scan<<<1, 1024, 0, stream>>>(deg, rowptr, wptr);
    k_fill<<<EB, 256, 0, stream>>>(src, dst, wptr, eid);

    // ---- layer 0
    k_gather128<<<GB, 256, 0, stream>>>(x0, rowptr, deg, eid, agg);
    hipMemsetAsync(stat, 0, 128 * sizeof(float), stream);
    k_mlp<128><<<RB, 256, 0, stream>>>(x0, agg, wA[0], bA[0], wB[0], bB[0], ybf, ssum, ssq);
    k_bn_fin<<<1, 64, 0, stream>>>(ssum, ssq, bnw[0], bnb[0], scale, shift);
    k_bn_apply<<<GB, 256, 0, stream>>>(ybf, scale, shift, x1);

    // ---- layers 1,2
    float* xin[4] = {x0, x1, x2, x3};
    for (int l = 1; l < 3; ++l) {
        k_gather64<<<GB, 256, 0, stream>>>(xin[l], rowptr, deg, eid, agg);
        hipMemsetAsync(stat, 0, 128 * sizeof(float), stream);
        k_mlp<64><<<RB, 256, 0, stream>>>(xin[l], agg, wA[l], bA[l], wB[l], bB[l], ybf, ssum, ssq);
        k_bn_fin<<<1, 64, 0, stream>>>(ssum, ssq, bnw[l], bnb[l], scale, shift);
        k_bn_apply<<<GB, 256, 0, stream>>>(ybf, scale, shift, xin[l + 1]);
    }

    hipMemsetAsync(stat, 0, 128 * sizeof(float), stream);
    k_fc1<<<RB, 256, 0, stream>>>(x0, x1, x2, x3, fc1_w, fc1_b, ybf, ssum, ssq);
    k_bn_fin<<<1, 64, 0, stream>>>(ssum, ssq, fcbn_w, fcbn_b, scale, shift);
    k_final<<<(N_NODES + 255) / 256, 256, 0, stream>>>(ybf, scale, shift, fc2_w, fc2_b, out);
}

// Round 5
// 944.262 us; speedup vs baseline: 7.7855x; 1.3083x over previous
//
#include <hip/hip_runtime.h>

// Problem constants (fixed by reference)
#define N_NODES 50000
#define E_EDGES 800000
#define BN_EPS 1e-5f
#define SLOPE 0.01f

// All float tensors are fp32; integer tensors int32; output fp32[N].

// ---------------------------------------------------------------------------
// K0: x0[n] = concat(emb_deg[deg[n]], emb_lab[lab[n]])  -> [N,128] fp32
// ---------------------------------------------------------------------------
__global__ void k_build_x0(const float* __restrict__ ed, const float* __restrict__ el,
                           const int* __restrict__ nd, const int* __restrict__ nl,
                           float* __restrict__ x0) {
    int idx = blockIdx.x * blockDim.x + threadIdx.x;  // N*64
    if (idx >= N_NODES * 64) return;
    int n = idx >> 6, c = idx & 63;
    x0[(size_t)n * 128 + c]      = ed[nd[n] * 64 + c];
    x0[(size_t)n * 128 + 64 + c] = el[nl[n] * 64 + c];
}

// ---------------------------------------------------------------------------
// CSR build: degree histogram -> exclusive scan -> bucket fill
// ---------------------------------------------------------------------------
__global__ void k_deg(const int* __restrict__ dst, int* __restrict__ deg) {
    int e = blockIdx.x * blockDim.x + threadIdx.x;
    if (e >= E_EDGES) return;
    atomicAdd(&deg[dst[e]], 1);
}

__global__ __launch_bounds__(1024) void k_scan(const int* __restrict__ deg,
        int* __restrict__ rowptr, int* __restrict__ wptr) {
    __shared__ int part[1024];
    int t = threadIdx.x;
    const int PER = (N_NODES + 1023) / 1024;  // 49
    int base = t * PER;
    int s = 0;
    for (int i = 0; i < PER; ++i) {
        int idx = base + i;
        if (idx < N_NODES) s += deg[idx];
    }
    part[t] = s;
    __syncthreads();
    for (int off = 1; off < 1024; off <<= 1) {
        int v = (t >= off) ? part[t - off] : 0;
        __syncthreads();
        part[t] += v;
        __syncthreads();
    }
    int run = (t == 0) ? 0 : part[t - 1];
    for (int i = 0; i < PER; ++i) {
        int idx = base + i;
        if (idx < N_NODES) {
            rowptr[idx] = run;
            wptr[idx]   = run;
            run += deg[idx];
        }
    }
}

__global__ void k_fill(const int* __restrict__ src, const int* __restrict__ dst,
                       int* __restrict__ wptr, int* __restrict__ eid) {
    int e = blockIdx.x * blockDim.x + threadIdx.x;
    if (e >= E_EDGES) return;
    int pos = atomicAdd(&wptr[dst[e]], 1);
    eid[pos] = src[e];
}

// ---------------------------------------------------------------------------
// Gather: one wave per dst node, lane = column. Zero atomics.
// ---------------------------------------------------------------------------
__global__ __launch_bounds__(256) void k_gather64(const float* __restrict__ x,
        const int* __restrict__ rowptr, const int* __restrict__ deg,
        const int* __restrict__ eid, float* __restrict__ agg) {
    int gid = blockIdx.x * blockDim.x + threadIdx.x;
    int node = gid >> 6, lane = gid & 63;
    if (node >= N_NODES) return;
    int start = rowptr[node], n = deg[node];
    float a0 = 0.f, a1 = 0.f;
    int i = 0;
    for (; i + 2 <= n; i += 2) {
        int s0 = eid[start + i], s1 = eid[start + i + 1];
        a0 += x[(size_t)s0 * 64 + lane];
        a1 += x[(size_t)s1 * 64 + lane];
    }
    if (i < n) a0 += x[(size_t)eid[start + i] * 64 + lane];
    agg[(size_t)node * 64 + lane] = a0 + a1;
}

__global__ __launch_bounds__(256) void k_gather128(const float* __restrict__ x,
        const int* __restrict__ rowptr, const int* __restrict__ deg,
        const int* __restrict__ eid, float* __restrict__ agg) {
    int gid = blockIdx.x * blockDim.x + threadIdx.x;
    int node = gid >> 6, lane = gid & 63;
    if (node >= N_NODES) return;
    int start = rowptr[node], n = deg[node];
    float ax0 = 0.f, ay0 = 0.f, ax1 = 0.f, ay1 = 0.f;
    int i = 0;
    for (; i + 2 <= n; i += 2) {
        int s0 = eid[start + i], s1 = eid[start + i + 1];
        float2 v0 = *(const float2*)(x + (size_t)s0 * 128 + lane * 2);
        float2 v1 = *(const float2*)(x + (size_t)s1 * 128 + lane * 2);
        ax0 += v0.x; ay0 += v0.y; ax1 += v1.x; ay1 += v1.y;
    }
    if (i < n) {
        float2 v = *(const float2*)(x + (size_t)eid[start + i] * 128 + lane * 2);
        ax0 += v.x; ay0 += v.y;
    }
    *(float2*)(agg + (size_t)node * 128 + lane * 2) = make_float2(ax0 + ax1, ay0 + ay1);
}

// ---------------------------------------------------------------------------
// K2: fused GIN MLP, register-tiled 4 rows x C cols per thread.
// Thread t: rg = t&15 -> rows {rg+16*rr}; cg = t>>4 -> col group.
// One weight float4 load feeds 16 FMAs (4 rows x 4 K).
// ---------------------------------------------------------------------------
template<int D>
__global__ __launch_bounds__(256) void k_mlp(
        const float* __restrict__ x, const float* __restrict__ agg,
        const float* __restrict__ wa, const float* __restrict__ ba,
        const float* __restrict__ wb, const float* __restrict__ bb,
        float* __restrict__ ybuf, float* __restrict__ ssum, float* __restrict__ ssq) {
    constexpr int LDW = D + 4;   // row step 16*LDW -> 2-way max bank aliasing (free)
    constexpr int C1 = D / 16;   // lin1 cols per thread (8 or 4)
    __shared__ float xs[64 * LDW];
    int t = threadIdx.x, rg = t & 15, cg = t >> 4;
    int row0 = blockIdx.x * 64;

    // stage (x+agg) tile as float4
    constexpr int C4 = D / 4;
    for (int i4 = t; i4 < 64 * C4; i4 += 256) {
        int rr = i4 / C4, c4 = (i4 % C4) * 4;
        int g = row0 + rr;
        float4 v = make_float4(0.f, 0.f, 0.f, 0.f);
        if (g < N_NODES) {
            float4 a = *(const float4*)(x + (size_t)g * D + c4);
            float4 b = *(const float4*)(agg + (size_t)g * D + c4);
            v = make_float4(a.x + b.x, a.y + b.y, a.z + b.z, a.w + b.w);
        }
        *(float4*)(xs + rr * LDW + c4) = v;
    }
    __syncthreads();

    // ---- lin1 + lrelu (in place)
    float acc1[4][C1];
    #pragma unroll
    for (int cc = 0; cc < C1; ++cc) {
        float bv = ba[cg * C1 + cc];
        #pragma unroll
        for (int rr = 0; rr < 4; ++rr) acc1[rr][cc] = bv;
    }
    #pragma unroll 1
    for (int ks = 0; ks < D; ks += 4) {
        float4 xv[4];
        #pragma unroll
        for (int rr = 0; rr < 4; ++rr)
            xv[rr] = *(const float4*)(xs + (rg + 16 * rr) * LDW + ks);
        #pragma unroll
        for (int cc = 0; cc < C1; ++cc) {
            float4 wv = *(const float4*)(wa + (size_t)(cg * C1 + cc) * D + ks);
            #pragma unroll
            for (int rr = 0; rr < 4; ++rr)
                acc1[rr][cc] += xv[rr].x * wv.x + xv[rr].y * wv.y
                              + xv[rr].z * wv.z + xv[rr].w * wv.w;
        }
    }
    #pragma unroll
    for (int rr = 0; rr < 4; ++rr)
        #pragma unroll
        for (int cc = 0; cc < C1; ++cc) {
            float a = acc1[rr][cc];
            acc1[rr][cc] = a > 0.f ? a : SLOPE * a;
        }
    __syncthreads();              // all lin1 reads of xs done
    #pragma unroll
    for (int rr = 0; rr < 4; ++rr)
        #pragma unroll
        for (int cc = 0; cc < C1; cc += 4)
            *(float4*)(xs + (rg + 16 * rr) * LDW + cg * C1 + cc) =
                make_float4(acc1[rr][cc], acc1[rr][cc + 1], acc1[rr][cc + 2], acc1[rr][cc + 3]);
    __syncthreads();              // h tile visible

    // ---- lin2: N=64 (4 cols/thread), K=D
    float acc[4][4];
    #pragma unroll
    for (int cc = 0; cc < 4; ++cc) {
        float bv = bb[cg * 4 + cc];
        #pragma unroll
        for (int rr = 0; rr < 4; ++rr) acc[rr][cc] = bv;
    }
    #pragma unroll 1
    for (int ks = 0; ks < D; ks += 4) {
        float4 xv[4];
        #pragma unroll
        for (int rr = 0; rr < 4; ++rr)
            xv[rr] = *(const float4*)(xs + (rg + 16 * rr) * LDW + ks);
        #pragma unroll
        for (int cc = 0; cc < 4; ++cc) {
            float4 wv = *(const float4*)(wb + (size_t)(cg * 4 + cc) * D + ks);
            #pragma unroll
            for (int rr = 0; rr < 4; ++rr)
                acc[rr][cc] += xv[rr].x * wv.x + xv[rr].y * wv.y
                             + xv[rr].z * wv.z + xv[rr].w * wv.w;
        }
    }
    // write ybuf + BN stats
    float ps[4] = {0.f, 0.f, 0.f, 0.f}, pq[4] = {0.f, 0.f, 0.f, 0.f};
    #pragma unroll
    for (int rr = 0; rr < 4; ++rr) {
        int gr = row0 + rg + 16 * rr;
        bool ok = gr < N_NODES;
        if (ok)
            *(float4*)(ybuf + (size_t)gr * 64 + cg * 4) =
                make_float4(acc[rr][0], acc[rr][1], acc[rr][2], acc[rr][3]);
        #pragma unroll
        for (int cc = 0; cc < 4; ++cc) {
            float a = ok ? acc[rr][cc] : 0.f;
            ps[cc] += a; pq[cc] += a * a;
        }
    }
    #pragma unroll
    for (int o = 8; o; o >>= 1)
        #pragma unroll
        for (int cc = 0; cc < 4; ++cc) {
            ps[cc] += __shfl_down(ps[cc], o, 16);
            pq[cc] += __shfl_down(pq[cc], o, 16);
        }
    if (rg == 0) {   // one exclusive writer per column per block
        #pragma unroll
        for (int cc = 0; cc < 4; ++cc) {
            atomicAdd(&ssum[cg * 4 + cc], ps[cc]);
            atomicAdd(&ssq[cg * 4 + cc], pq[cc]);
        }
    }
}

// ---------------------------------------------------------------------------
// K3: BN finalize
// ---------------------------------------------------------------------------
__global__ void k_bn_fin(const float* __restrict__ ssum, const float* __restrict__ ssq,
                         const float* __restrict__ gw, const float* __restrict__ gb,
                         float* __restrict__ scale, float* __restrict__ shift) {
    int j = threadIdx.x;
    float m = ssum[j] * (1.0f / N_NODES);
    float v = ssq[j] * (1.0f / N_NODES) - m * m;
    float sc = gw[j] * rsqrtf(v + BN_EPS);
    scale[j] = sc;
    shift[j] = gb[j] - m * sc;
}

// ---------------------------------------------------------------------------
// K4: x_out = lrelu(y*scale + shift)
// ---------------------------------------------------------------------------
__global__ void k_bn_apply(const float* __restrict__ y, const float* __restrict__ scale,
                           const float* __restrict__ shift, float* __restrict__ xo) {
    int idx = blockIdx.x * blockDim.x + threadIdx.x;
    if (idx >= N_NODES * 64) return;
    int c = idx & 63;
    float v = y[idx] * scale[c] + shift[c];
    xo[idx] = v > 0.f ? v : SLOPE * v;
}

// ---------------------------------------------------------------------------
// K5: fc1 over concat [x0|x1|x2|x3] (K=320), register-tiled 4x4
// ---------------------------------------------------------------------------
template<int SD>
__device__ __forceinline__ void fc1_seg(const float* __restrict__ xp, int row0, int t,
        int rg, int cg, float* xs, const float* __restrict__ w, float (&acc)[4][4]) {
    constexpr int LDW = SD + 4;
    constexpr int C4 = SD / 4;
    __syncthreads();  // previous segment's xs reads done
    for (int i4 = t; i4 < 64 * C4; i4 += 256) {
        int rr = i4 / C4, c4 = (i4 % C4) * 4;
        int g = row0 + rr;
        float4 v = (g < N_NODES) ? *(const float4*)(xp + (size_t)g * SD + c4)
                                 : make_float4(0.f, 0.f, 0.f, 0.f);
        *(float4*)(xs + rr * LDW + c4) = v;
    }
    __syncthreads();
    #pragma unroll 1
    for (int ks = 0; ks < SD; ks += 4) {
        float4 xv[4];
        #pragma unroll
        for (int rr = 0; rr < 4; ++rr)
            xv[rr] = *(const float4*)(xs + (rg + 16 * rr) * LDW + ks);
        #pragma unroll
        for (int cc = 0; cc < 4; ++cc) {
            float4 wv = *(const float4*)(w + (size_t)(cg * 4 + cc) * 320 + ks);
            #pragma unroll
            for (int rr = 0; rr < 4; ++rr)
                acc[rr][cc] += xv[rr].x * wv.x + xv[rr].y * wv.y
                             + xv[rr].z * wv.z + xv[rr].w * wv.w;
        }
    }
}

__global__ __launch_bounds__(256) void k_fc1(
        const float* __restrict__ x0, const float* __restrict__ x1,
        const float* __restrict__ x2, const float* __restrict__ x3,
        const float* __restrict__ w, const float* __restrict__ b,
        float* __restrict__ ybuf, float* __restrict__ ssum, float* __restrict__ ssq) {
    __shared__ float xs[64 * 132];
    int t = threadIdx.x, rg = t & 15, cg = t >> 4;
    int row0 = blockIdx.x * 64;
    float acc[4][4];
    #pragma unroll
    for (int cc = 0; cc < 4; ++cc) {
        float bv = b[cg * 4 + cc];
        #pragma unroll
        for (int rr = 0; rr < 4; ++rr) acc[rr][cc] = bv;
    }
    fc1_seg<128>(x0, row0, t, rg, cg, xs, w + 0,   acc);
    fc1_seg<64> (x1, row0, t, rg, cg, xs, w + 128, acc);
    fc1_seg<64> (x2, row0, t, rg, cg, xs, w + 192, acc);
    fc1_seg<64> (x3, row0, t, rg, cg, xs, w + 256, acc);

    float ps[4] = {0.f, 0.f, 0.f, 0.f}, pq[4] = {0.f, 0.f, 0.f, 0.f};
    #pragma unroll
    for (int rr = 0; rr < 4; ++rr) {
        int gr = row0 + rg + 16 * rr;
        bool ok = gr < N_NODES;
        if (ok)
            *(float4*)(ybuf + (size_t)gr * 64 + cg * 4) =
                make_float4(acc[rr][0], acc[rr][1], acc[rr][2], acc[rr][3]);
        #pragma unroll
        for (int cc = 0; cc < 4; ++cc) {
            float a = ok ? acc[rr][cc] : 0.f;
            ps[cc] += a; pq[cc] += a * a;
        }
    }
    #pragma unroll
    for (int o = 8; o; o >>= 1)
        #pragma unroll
        for (int cc = 0; cc < 4; ++cc) {
            ps[cc] += __shfl_down(ps[cc], o, 16);
            pq[cc] += __shfl_down(pq[cc], o, 16);
        }
    if (rg == 0) {
        #pragma unroll
        for (int cc = 0; cc < 4; ++cc) {
            atomicAdd(&ssum[cg * 4 + cc], ps[cc]);
            atomicAdd(&ssq[cg * 4 + cc], pq[cc]);
        }
    }
}

// ---------------------------------------------------------------------------
// K6: out = sigmoid( fc2_w . lrelu(y*scale+shift) + fc2_b )
// ---------------------------------------------------------------------------
__global__ void k_final(const float* __restrict__ y, const float* __restrict__ scale,
                        const float* __restrict__ shift, const float* __restrict__ w2,
                        const float* __restrict__ b2, float* __restrict__ out) {
    __shared__ float sc[64], sh[64], w[64];
    int t = threadIdx.x;
    if (t < 64) { sc[t] = scale[t]; sh[t] = shift[t]; w[t] = w2[t]; }
    __syncthreads();
    int i = blockIdx.x * blockDim.x + t;
    if (i >= N_NODES) return;
    float z = b2[0];
    const float* row = y + (size_t)i * 64;
    #pragma unroll
    for (int c = 0; c < 64; c += 4) {
        float4 v4 = *(const float4*)(row + c);
        float v;
        v = v4.x * sc[c]   + sh[c];   v = v > 0.f ? v : SLOPE * v; z += v * w[c];
        v = v4.y * sc[c+1] + sh[c+1]; v = v > 0.f ? v : SLOPE * v; z += v * w[c+1];
        v = v4.z * sc[c+2] + sh[c+2]; v = v > 0.f ? v : SLOPE * v; z += v * w[c+2];
        v = v4.w * sc[c+3] + sh[c+3]; v = v > 0.f ? v : SLOPE * v; z += v * w[c+3];
    }
    out[i] = 1.f / (1.f + __expf(-z));
}

// ---------------------------------------------------------------------------
extern "C" void kernel_launch(void* const* d_in, const int* in_sizes, int n_in,
                              void* d_out, int out_size, void* d_ws, size_t ws_size,
                              hipStream_t stream) {
    const float* emb_deg = (const float*)d_in[0];
    const float* emb_lab = (const float*)d_in[1];
    const float* wA[3]  = {(const float*)d_in[2],  (const float*)d_in[8],  (const float*)d_in[14]};
    const float* bA[3]  = {(const float*)d_in[3],  (const float*)d_in[9],  (const float*)d_in[15]};
    const float* wB[3]  = {(const float*)d_in[4],  (const float*)d_in[10], (const float*)d_in[16]};
    const float* bB[3]  = {(const float*)d_in[5],  (const float*)d_in[11], (const float*)d_in[17]};
    const float* bnw[3] = {(const float*)d_in[6],  (const float*)d_in[12], (const float*)d_in[18]};
    const float* bnb[3] = {(const float*)d_in[7],  (const float*)d_in[13], (const float*)d_in[19]};
    const float* fc1_w  = (const float*)d_in[20];
    const float* fc1_b  = (const float*)d_in[21];
    const float* fcbn_w = (const float*)d_in[22];
    const float* fcbn_b = (const float*)d_in[23];
    const float* fc2_w  = (const float*)d_in[24];
    const float* fc2_b  = (const float*)d_in[25];
    const int* node_deg = (const int*)d_in[26];
    const int* node_lab = (const int*)d_in[27];
    const int* src = (const int*)d_in[28];
    const int* dst = src + E_EDGES;
    float* out = (float*)d_out;

    // workspace layout
    float* ws  = (float*)d_ws;
    float* x0  = ws;                               // N*128
    float* x1  = x0  + (size_t)N_NODES * 128;      // N*64
    float* x2  = x1  + (size_t)N_NODES * 64;       // N*64
    float* x3  = x2  + (size_t)N_NODES * 64;       // N*64
    float* agg = x3  + (size_t)N_NODES * 64;       // N*128
    float* ybf = agg + (size_t)N_NODES * 128;      // N*64
    float* stat = ybf + (size_t)N_NODES * 64;      // 256 floats
    float* ssum = stat, *ssq = stat + 64, *scale = stat + 128, *shift = stat + 192;
    // CSR arrays (int) after stat
    int* deg    = (int*)(stat + 256);              // N
    int* rowptr = deg + N_NODES;                   // N
    int* wptr   = rowptr + N_NODES;                // N
    int* eid    = wptr + N_NODES;                  // E

    const int RB = (N_NODES + 63) / 64;            // 782 row-tile blocks
    const int GB = (N_NODES * 64 + 255) / 256;     // 12500 gather blocks
    const int EB = (E_EDGES + 255) / 256;          // 3125 edge blocks

    k_build_x0<<<GB, 256, 0, stream>>>(emb_deg, emb_lab, node_deg, node_lab, x0);

    // ---- CSR build (per launch; identical work every call)
    hipMemsetAsync(deg, 0, N_NODES * sizeof(int), stream);
    k_deg<<<EB, 256, 0, stream>>>(dst, deg);
    k_scan<<<1, 1024, 0, stream>>>(deg, rowptr, wptr);
    k_fill<<<EB, 256, 0, stream>>>(src, dst, wptr, eid);

    // ---- layer 0
    k_gather128<<<GB, 256, 0, stream>>>(x0, rowptr, deg, eid, agg);
    hipMemsetAsync(stat, 0, 128 * sizeof(float), stream);
    k_mlp<128><<<RB, 256, 0, stream>>>(x0, agg, wA[0], bA[0], wB[0], bB[0], ybf, ssum, ssq);
    k_bn_fin<<<1, 64, 0, stream>>>(ssum, ssq, bnw[0], bnb[0], scale, shift);
    k_bn_apply<<<GB, 256, 0, stream>>>(ybf, scale, shift, x1);

    // ---- layers 1,2
    float* xin[4] = {x0, x1, x2, x3};
    for (int l = 1; l < 3; ++l) {
        k_gather64<<<GB, 256, 0, stream>>>(xin[l], rowptr, deg, eid, agg);
        hipMemsetAsync(stat, 0, 128 * sizeof(float), stream);
        k_mlp<64><<<RB, 256, 0, stream>>>(xin[l], agg, wA[l], bA[l], wB[l], bB[l], ybf, ssum, ssq);
        k_bn_fin<<<1, 64, 0, stream>>>(ssum, ssq, bnw[l], bnb[l], scale, shift);
        k_bn_apply<<<GB, 256, 0, stream>>>(ybf, scale, shift, xin[l + 1]);
    }

    hipMemsetAsync(stat, 0, 128 * sizeof(float), stream);
    k_fc1<<<RB, 256, 0, stream>>>(x0, x1, x2, x3, fc1_w, fc1_b, ybf, ssum, ssq);
    k_bn_fin<<<1, 64, 0, stream>>>(ssum, ssq, fcbn_w, fcbn_b, scale, shift);
    k_final<<<(N_NODES + 255) / 256, 256, 0, stream>>>(ybf, scale, shift, fc2_w, fc2_b, out);
}

// Round 6
// 890.815 us; speedup vs baseline: 8.2526x; 1.0600x over previous
//
#include <hip/hip_runtime.h>

// Problem constants (fixed by reference)
#define N_NODES 50000
#define E_EDGES 800000
#define BN_EPS 1e-5f
#define SLOPE 0.01f

// All float tensors are fp32; integer tensors int32; output fp32[N].

// ---------------------------------------------------------------------------
// K0: x0[n] = concat(emb_deg[deg[n]], emb_lab[lab[n]])  -> [N,128] fp32
// ---------------------------------------------------------------------------
__global__ void k_build_x0(const float* __restrict__ ed, const float* __restrict__ el,
                           const int* __restrict__ nd, const int* __restrict__ nl,
                           float* __restrict__ x0) {
    int idx = blockIdx.x * blockDim.x + threadIdx.x;  // N*64
    if (idx >= N_NODES * 64) return;
    int n = idx >> 6, c = idx & 63;
    x0[(size_t)n * 128 + c]      = ed[nd[n] * 64 + c];
    x0[(size_t)n * 128 + 64 + c] = el[nl[n] * 64 + c];
}

// ---------------------------------------------------------------------------
// CSR build: degree histogram -> exclusive scan -> bucket fill
// ---------------------------------------------------------------------------
__global__ void k_deg(const int* __restrict__ dst, int* __restrict__ deg) {
    int e = blockIdx.x * blockDim.x + threadIdx.x;
    if (e >= E_EDGES) return;
    atomicAdd(&deg[dst[e]], 1);
}

__global__ __launch_bounds__(1024) void k_scan(const int* __restrict__ deg,
        int* __restrict__ rowptr, int* __restrict__ wptr) {
    __shared__ int part[1024];
    int t = threadIdx.x;
    const int PER = (N_NODES + 1023) / 1024;  // 49
    int base = t * PER;
    int s = 0;
    for (int i = 0; i < PER; ++i) {
        int idx = base + i;
        if (idx < N_NODES) s += deg[idx];
    }
    part[t] = s;
    __syncthreads();
    for (int off = 1; off < 1024; off <<= 1) {
        int v = (t >= off) ? part[t - off] : 0;
        __syncthreads();
        part[t] += v;
        __syncthreads();
    }
    int run = (t == 0) ? 0 : part[t - 1];
    for (int i = 0; i < PER; ++i) {
        int idx = base + i;
        if (idx < N_NODES) {
            rowptr[idx] = run;
            wptr[idx]   = run;
            run += deg[idx];
        }
    }
}

__global__ void k_fill(const int* __restrict__ src, const int* __restrict__ dst,
                       int* __restrict__ wptr, int* __restrict__ eid) {
    int e = blockIdx.x * blockDim.x + threadIdx.x;
    if (e >= E_EDGES) return;
    int pos = atomicAdd(&wptr[dst[e]], 1);
    eid[pos] = src[e];
}

// ---------------------------------------------------------------------------
// K2: fused gather + GIN MLP. Tile = 32 rows, 256 threads (4 waves).
// Staging: wave w gathers nodes w*8..w*8+7 (self + CSR neighbors) straight
// from x (coalesced row reads, L2/LLC-served) into xs.
// GEMM: thread t: rg=t&7 -> rows {rg+8*rr}; cg=t>>3 -> col group.
// One weight float4 load feeds 16 FMAs. Stats -> per-layer global buffer.
// ---------------------------------------------------------------------------
template<int D>
__global__ __launch_bounds__(256, 6) void k_mlp(
        const float* __restrict__ x,
        const int* __restrict__ rowptr, const int* __restrict__ cdeg,
        const int* __restrict__ eid,
        const float* __restrict__ wa, const float* __restrict__ ba,
        const float* __restrict__ wb, const float* __restrict__ bb,
        float* __restrict__ ybuf, float* __restrict__ st) {
    constexpr int LDW = D + 4;   // %32==4 -> 8-lane row group on distinct banks
    constexpr int C1 = D / 32;   // lin1 cols per thread (4 or 2)
    __shared__ float xs[32 * LDW];
    int t = threadIdx.x;
    int row0 = blockIdx.x * 32;

    // ---- staging: gather self + neighbors
    {
        int lane = t & 63, wv = t >> 6;
        for (int i = 0; i < 8; ++i) {
            int lr = wv * 8 + i;
            int node = row0 + lr;
            if constexpr (D == 64) {
                float a0 = 0.f, a1 = 0.f;
                if (node < N_NODES) {
                    int start = rowptr[node], n = cdeg[node];
                    a0 = x[(size_t)node * 64 + lane];
                    int j = 0;
                    for (; j + 2 <= n; j += 2) {
                        int s0 = eid[start + j], s1 = eid[start + j + 1];
                        a0 += x[(size_t)s0 * 64 + lane];
                        a1 += x[(size_t)s1 * 64 + lane];
                    }
                    if (j < n) a0 += x[(size_t)eid[start + j] * 64 + lane];
                }
                xs[lr * LDW + lane] = a0 + a1;
            } else {
                float ax0 = 0.f, ay0 = 0.f, ax1 = 0.f, ay1 = 0.f;
                if (node < N_NODES) {
                    int start = rowptr[node], n = cdeg[node];
                    float2 sv = *(const float2*)(x + (size_t)node * 128 + lane * 2);
                    ax0 = sv.x; ay0 = sv.y;
                    int j = 0;
                    for (; j + 2 <= n; j += 2) {
                        int s0 = eid[start + j], s1 = eid[start + j + 1];
                        float2 v0 = *(const float2*)(x + (size_t)s0 * 128 + lane * 2);
                        float2 v1 = *(const float2*)(x + (size_t)s1 * 128 + lane * 2);
                        ax0 += v0.x; ay0 += v0.y; ax1 += v1.x; ay1 += v1.y;
                    }
                    if (j < n) {
                        float2 v = *(const float2*)(x + (size_t)eid[start + j] * 128 + lane * 2);
                        ax0 += v.x; ay0 += v.y;
                    }
                }
                *(float2*)(xs + lr * LDW + lane * 2) = make_float2(ax0 + ax1, ay0 + ay1);
            }
        }
    }
    __syncthreads();

    int rg = t & 7, cg = t >> 3;

    // ---- lin1 + lrelu
    float acc1[4][C1];
    #pragma unroll
    for (int cc = 0; cc < C1; ++cc) {
        float bv = ba[cg * C1 + cc];
        #pragma unroll
        for (int rr = 0; rr < 4; ++rr) acc1[rr][cc] = bv;
    }
    #pragma unroll 1
    for (int ks = 0; ks < D; ks += 4) {
        float4 xv[4];
        #pragma unroll
        for (int rr = 0; rr < 4; ++rr)
            xv[rr] = *(const float4*)(xs + (rg + 8 * rr) * LDW + ks);
        #pragma unroll
        for (int cc = 0; cc < C1; ++cc) {
            float4 wv = *(const float4*)(wa + (size_t)(cg * C1 + cc) * D + ks);
            #pragma unroll
            for (int rr = 0; rr < 4; ++rr)
                acc1[rr][cc] += xv[rr].x * wv.x + xv[rr].y * wv.y
                              + xv[rr].z * wv.z + xv[rr].w * wv.w;
        }
    }
    #pragma unroll
    for (int rr = 0; rr < 4; ++rr)
        #pragma unroll
        for (int cc = 0; cc < C1; ++cc) {
            float a = acc1[rr][cc];
            acc1[rr][cc] = a > 0.f ? a : SLOPE * a;
        }
    __syncthreads();              // all lin1 reads of xs done
    #pragma unroll
    for (int rr = 0; rr < 4; ++rr) {
        if constexpr (C1 == 4)
            *(float4*)(xs + (rg + 8 * rr) * LDW + cg * 4) =
                make_float4(acc1[rr][0], acc1[rr][1], acc1[rr][2], acc1[rr][3]);
        else
            *(float2*)(xs + (rg + 8 * rr) * LDW + cg * 2) =
                make_float2(acc1[rr][0], acc1[rr][1]);
    }
    __syncthreads();              // h tile visible

    // ---- lin2: 64 outputs, 2 cols/thread
    float acc[4][2];
    #pragma unroll
    for (int cc = 0; cc < 2; ++cc) {
        float bv = bb[cg * 2 + cc];
        #pragma unroll
        for (int rr = 0; rr < 4; ++rr) acc[rr][cc] = bv;
    }
    #pragma unroll 1
    for (int ks = 0; ks < D; ks += 4) {
        float4 xv[4];
        #pragma unroll
        for (int rr = 0; rr < 4; ++rr)
            xv[rr] = *(const float4*)(xs + (rg + 8 * rr) * LDW + ks);
        #pragma unroll
        for (int cc = 0; cc < 2; ++cc) {
            float4 wv = *(const float4*)(wb + (size_t)(cg * 2 + cc) * D + ks);
            #pragma unroll
            for (int rr = 0; rr < 4; ++rr)
                acc[rr][cc] += xv[rr].x * wv.x + xv[rr].y * wv.y
                             + xv[rr].z * wv.z + xv[rr].w * wv.w;
        }
    }
    // write ybuf + BN stats
    float ps[2] = {0.f, 0.f}, pq[2] = {0.f, 0.f};
    #pragma unroll
    for (int rr = 0; rr < 4; ++rr) {
        int gr = row0 + rg + 8 * rr;
        bool ok = gr < N_NODES;
        if (ok)
            *(float2*)(ybuf + (size_t)gr * 64 + cg * 2) = make_float2(acc[rr][0], acc[rr][1]);
        #pragma unroll
        for (int cc = 0; cc < 2; ++cc) {
            float a = ok ? acc[rr][cc] : 0.f;
            ps[cc] += a; pq[cc] += a * a;
        }
    }
    #pragma unroll
    for (int o = 4; o; o >>= 1)
        #pragma unroll
        for (int cc = 0; cc < 2; ++cc) {
            ps[cc] += __shfl_down(ps[cc], o, 8);
            pq[cc] += __shfl_down(pq[cc], o, 8);
        }
    if (rg == 0) {
        #pragma unroll
        for (int cc = 0; cc < 2; ++cc) {
            atomicAdd(&st[cg * 2 + cc], ps[cc]);
            atomicAdd(&st[64 + cg * 2 + cc], pq[cc]);
        }
    }
}

// ---------------------------------------------------------------------------
// K4: x_out = lrelu(y*scale + shift); scale/shift computed inline from stats
// ---------------------------------------------------------------------------
__global__ void k_bn_apply(const float* __restrict__ y, const float* __restrict__ st,
                           const float* __restrict__ gw, const float* __restrict__ gb,
                           float* __restrict__ xo) {
    __shared__ float sc[64], sh[64];
    int t = threadIdx.x;
    if (t < 64) {
        float m = st[t] * (1.0f / N_NODES);
        float v = st[64 + t] * (1.0f / N_NODES) - m * m;
        float s = gw[t] * rsqrtf(v + BN_EPS);
        sc[t] = s; sh[t] = gb[t] - m * s;
    }
    __syncthreads();
    int idx = blockIdx.x * blockDim.x + t;
    if (idx >= N_NODES * 64) return;
    int c = idx & 63;
    float v = y[idx] * sc[c] + sh[c];
    xo[idx] = v > 0.f ? v : SLOPE * v;
}

// ---------------------------------------------------------------------------
// K5: fc1 over concat [x0|x1|x2|x3] (K=320), 32-row tiles, 4x2 reg tile
// ---------------------------------------------------------------------------
template<int SD>
__device__ __forceinline__ void fc1_seg(const float* __restrict__ xp, int row0, int t,
        int rg, int cg, float* xs, const float* __restrict__ w, float (&acc)[4][2]) {
    constexpr int LDW = SD + 4;
    constexpr int C4 = SD / 4;
    __syncthreads();  // previous segment's xs reads done
    for (int i4 = t; i4 < 32 * C4; i4 += 256) {
        int rr = i4 / C4, c4 = (i4 % C4) * 4;
        int g = row0 + rr;
        float4 v = (g < N_NODES) ? *(const float4*)(xp + (size_t)g * SD + c4)
                                 : make_float4(0.f, 0.f, 0.f, 0.f);
        *(float4*)(xs + rr * LDW + c4) = v;
    }
    __syncthreads();
    #pragma unroll 1
    for (int ks = 0; ks < SD; ks += 4) {
        float4 xv[4];
        #pragma unroll
        for (int rr = 0; rr < 4; ++rr)
            xv[rr] = *(const float4*)(xs + (rg + 8 * rr) * LDW + ks);
        #pragma unroll
        for (int cc = 0; cc < 2; ++cc) {
            float4 wv = *(const float4*)(w + (size_t)(cg * 2 + cc) * 320 + ks);
            #pragma unroll
            for (int rr = 0; rr < 4; ++rr)
                acc[rr][cc] += xv[rr].x * wv.x + xv[rr].y * wv.y
                             + xv[rr].z * wv.z + xv[rr].w * wv.w;
        }
    }
}

__global__ __launch_bounds__(256, 6) void k_fc1(
        const float* __restrict__ x0, const float* __restrict__ x1,
        const float* __restrict__ x2, const float* __restrict__ x3,
        const float* __restrict__ w, const float* __restrict__ b,
        float* __restrict__ ybuf, float* __restrict__ st) {
    __shared__ float xs[32 * 132];
    int t = threadIdx.x, rg = t & 7, cg = t >> 3;
    int row0 = blockIdx.x * 32;
    float acc[4][2];
    #pragma unroll
    for (int cc = 0; cc < 2; ++cc) {
        float bv = b[cg * 2 + cc];
        #pragma unroll
        for (int rr = 0; rr < 4; ++rr) acc[rr][cc] = bv;
    }
    fc1_seg<128>(x0, row0, t, rg, cg, xs, w + 0,   acc);
    fc1_seg<64> (x1, row0, t, rg, cg, xs, w + 128, acc);
    fc1_seg<64> (x2, row0, t, rg, cg, xs, w + 192, acc);
    fc1_seg<64> (x3, row0, t, rg, cg, xs, w + 256, acc);

    float ps[2] = {0.f, 0.f}, pq[2] = {0.f, 0.f};
    #pragma unroll
    for (int rr = 0; rr < 4; ++rr) {
        int gr = row0 + rg + 8 * rr;
        bool ok = gr < N_NODES;
        if (ok)
            *(float2*)(ybuf + (size_t)gr * 64 + cg * 2) = make_float2(acc[rr][0], acc[rr][1]);
        #pragma unroll
        for (int cc = 0; cc < 2; ++cc) {
            float a = ok ? acc[rr][cc] : 0.f;
            ps[cc] += a; pq[cc] += a * a;
        }
    }
    #pragma unroll
    for (int o = 4; o; o >>= 1)
        #pragma unroll
        for (int cc = 0; cc < 2; ++cc) {
            ps[cc] += __shfl_down(ps[cc], o, 8);
            pq[cc] += __shfl_down(pq[cc], o, 8);
        }
    if (rg == 0) {
        #pragma unroll
        for (int cc = 0; cc < 2; ++cc) {
            atomicAdd(&st[cg * 2 + cc], ps[cc]);
            atomicAdd(&st[64 + cg * 2 + cc], pq[cc]);
        }
    }
}

// ---------------------------------------------------------------------------
// K6: out = sigmoid( fc2_w . lrelu(bn(y)) + fc2_b ); bn from stats inline
// ---------------------------------------------------------------------------
__global__ void k_final(const float* __restrict__ y, const float* __restrict__ st,
                        const float* __restrict__ gw, const float* __restrict__ gb,
                        const float* __restrict__ w2, const float* __restrict__ b2,
                        float* __restrict__ out) {
    __shared__ float sc[64], sh[64], w[64];
    int t = threadIdx.x;
    if (t < 64) {
        float m = st[t] * (1.0f / N_NODES);
        float v = st[64 + t] * (1.0f / N_NODES) - m * m;
        float s = gw[t] * rsqrtf(v + BN_EPS);
        sc[t] = s; sh[t] = gb[t] - m * s; w[t] = w2[t];
    }
    __syncthreads();
    int i = blockIdx.x * blockDim.x + t;
    if (i >= N_NODES) return;
    float z = b2[0];
    const float* row = y + (size_t)i * 64;
    #pragma unroll
    for (int c = 0; c < 64; c += 4) {
        float4 v4 = *(const float4*)(row + c);
        float v;
        v = v4.x * sc[c]   + sh[c];   v = v > 0.f ? v : SLOPE * v; z += v * w[c];
        v = v4.y * sc[c+1] + sh[c+1]; v = v > 0.f ? v : SLOPE * v; z += v * w[c+1];
        v = v4.z * sc[c+2] + sh[c+2]; v = v > 0.f ? v : SLOPE * v; z += v * w[c+2];
        v = v4.w * sc[c+3] + sh[c+3]; v = v > 0.f ? v : SLOPE * v; z += v * w[c+3];
    }
    out[i] = 1.f / (1.f + __expf(-z));
}

// ---------------------------------------------------------------------------
extern "C" void kernel_launch(void* const* d_in, const int* in_sizes, int n_in,
                              void* d_out, int out_size, void* d_ws, size_t ws_size,
                              hipStream_t stream) {
    const float* emb_deg = (const float*)d_in[0];
    const float* emb_lab = (const float*)d_in[1];
    const float* wA[3]  = {(const float*)d_in[2],  (const float*)d_in[8],  (const float*)d_in[14]};
    const float* bA[3]  = {(const float*)d_in[3],  (const float*)d_in[9],  (const float*)d_in[15]};
    const float* wB[3]  = {(const float*)d_in[4],  (const float*)d_in[10], (const float*)d_in[16]};
    const float* bB[3]  = {(const float*)d_in[5],  (const float*)d_in[11], (const float*)d_in[17]};
    const float* bnw[3] = {(const float*)d_in[6],  (const float*)d_in[12], (const float*)d_in[18]};
    const float* bnb[3] = {(const float*)d_in[7],  (const float*)d_in[13], (const float*)d_in[19]};
    const float* fc1_w  = (const float*)d_in[20];
    const float* fc1_b  = (const float*)d_in[21];
    const float* fcbn_w = (const float*)d_in[22];
    const float* fcbn_b = (const float*)d_in[23];
    const float* fc2_w  = (const float*)d_in[24];
    const float* fc2_b  = (const float*)d_in[25];
    const int* node_deg = (const int*)d_in[26];
    const int* node_lab = (const int*)d_in[27];
    const int* src = (const int*)d_in[28];
    const int* dst = src + E_EDGES;
    float* out = (float*)d_out;

    // workspace layout
    float* ws  = (float*)d_ws;
    float* x0  = ws;                               // N*128
    float* x1  = x0  + (size_t)N_NODES * 128;      // N*64
    float* x2  = x1  + (size_t)N_NODES * 64;       // N*64
    float* x3  = x2  + (size_t)N_NODES * 64;       // N*64
    float* ybf = x3  + (size_t)N_NODES * 64;       // N*64
    float* stat = ybf + (size_t)N_NODES * 64;      // 4 layers x 128 floats
    int* cdeg   = (int*)(stat + 512);              // N  (contiguous w/ stat)
    int* rowptr = cdeg + N_NODES;                  // N
    int* wptr   = rowptr + N_NODES;                // N
    int* eid    = wptr + N_NODES;                  // E

    const int RB = (N_NODES + 31) / 32;            // 1563 row-tile blocks
    const int GB = (N_NODES * 64 + 255) / 256;     // 12500 elementwise blocks
    const int EB = (E_EDGES + 255) / 256;          // 3125 edge blocks

    // one memset: stats (512 floats) + cdeg (N ints), contiguous
    hipMemsetAsync(stat, 0, (512 + N_NODES) * sizeof(float), stream);

    k_build_x0<<<GB, 256, 0, stream>>>(emb_deg, emb_lab, node_deg, node_lab, x0);

    // ---- CSR build (per launch; identical work every call)
    k_deg<<<EB, 256, 0, stream>>>(dst, cdeg);
    k_scan<<<1, 1024, 0, stream>>>(cdeg, rowptr, wptr);
    k_fill<<<EB, 256, 0, stream>>>(src, dst, wptr, eid);

    // ---- 3 GIN layers (gather fused into MLP staging)
    float* xin[4] = {x0, x1, x2, x3};
    for (int l = 0; l < 3; ++l) {
        float* st = stat + l * 128;
        if (l == 0)
            k_mlp<128><<<RB, 256, 0, stream>>>(xin[l], rowptr, cdeg, eid,
                wA[l], bA[l], wB[l], bB[l], ybf, st);
        else
            k_mlp<64><<<RB, 256, 0, stream>>>(xin[l], rowptr, cdeg, eid,
                wA[l], bA[l], wB[l], bB[l], ybf, st);
        k_bn_apply<<<GB, 256, 0, stream>>>(ybf, st, bnw[l], bnb[l], xin[l + 1]);
    }

    k_fc1<<<RB, 256, 0, stream>>>(x0, x1, x2, x3, fc1_w, fc1_b, ybf, stat + 384);
    k_final<<<(N_NODES + 255) / 256, 256, 0, stream>>>(ybf, stat + 384, fcbn_w, fcbn_b,
                                                       fc2_w, fc2_b, out);
}

// Round 7
// 794.366 us; speedup vs baseline: 9.2546x; 1.1214x over previous
//
#include <hip/hip_runtime.h>

// Problem constants (fixed by reference)
#define N_NODES 50000
#define E_EDGES 800000
#define BN_EPS 1e-5f
#define SLOPE 0.01f

// All float tensors are fp32; integer tensors int32; output fp32[N].

// ---------------------------------------------------------------------------
// K0: x0[n] = concat(emb_deg[deg[n]], emb_lab[lab[n]])  (needed for fc1)
// ---------------------------------------------------------------------------
__global__ void k_build_x0(const float* __restrict__ ed, const float* __restrict__ el,
                           const int* __restrict__ nd, const int* __restrict__ nl,
                           float* __restrict__ x0) {
    int idx = blockIdx.x * blockDim.x + threadIdx.x;  // N*64
    if (idx >= N_NODES * 64) return;
    int n = idx >> 6, c = idx & 63;
    x0[(size_t)n * 128 + c]      = ed[nd[n] * 64 + c];
    x0[(size_t)n * 128 + 64 + c] = el[nl[n] * 64 + c];
}

// K-cls: packed class per node
__global__ void k_cls(const int* __restrict__ nd, const int* __restrict__ nl,
                      int* __restrict__ ncls) {
    int n = blockIdx.x * blockDim.x + threadIdx.x;
    if (n < N_NODES) ncls[n] = nd[n] | (nl[n] << 16);
}

// ---------------------------------------------------------------------------
// CSR build: degree histogram -> exclusive scan -> bucket fill (+edge cls)
// ---------------------------------------------------------------------------
__global__ void k_deg(const int* __restrict__ dst, int* __restrict__ deg) {
    int e = blockIdx.x * blockDim.x + threadIdx.x;
    if (e >= E_EDGES) return;
    atomicAdd(&deg[dst[e]], 1);
}

__global__ __launch_bounds__(1024) void k_scan(const int* __restrict__ deg,
        int* __restrict__ rowptr, int* __restrict__ wptr) {
    __shared__ int part[1024];
    int t = threadIdx.x;
    const int PER = (N_NODES + 1023) / 1024;  // 49
    int base = t * PER;
    int s = 0;
    for (int i = 0; i < PER; ++i) {
        int idx = base + i;
        if (idx < N_NODES) s += deg[idx];
    }
    part[t] = s;
    __syncthreads();
    for (int off = 1; off < 1024; off <<= 1) {
        int v = (t >= off) ? part[t - off] : 0;
        __syncthreads();
        part[t] += v;
        __syncthreads();
    }
    int run = (t == 0) ? 0 : part[t - 1];
    for (int i = 0; i < PER; ++i) {
        int idx = base + i;
        if (idx < N_NODES) {
            rowptr[idx] = run;
            wptr[idx]   = run;
            run += deg[idx];
        }
    }
}

__global__ void k_fill(const int* __restrict__ src, const int* __restrict__ dst,
                       const int* __restrict__ ncls,
                       int* __restrict__ wptr, int* __restrict__ eid,
                       int* __restrict__ ecls) {
    int e = blockIdx.x * blockDim.x + threadIdx.x;
    if (e >= E_EDGES) return;
    int s = src[e];
    int pos = atomicAdd(&wptr[dst[e]], 1);
    eid[pos]  = s;
    ecls[pos] = ncls[s];
}

// ---------------------------------------------------------------------------
// K2: fused gather + GIN MLP. Tile = 16 rows, 256 threads (4 waves), each
// wave stages 4 nodes. D=128 (layer 0): neighbor rows come from the 80-row
// emb dictionary (L1-resident) via packed edge classes -- no x-row traffic.
// D=64: eids batch-loaded 64/lane-coalesced, __shfl broadcast, 4 acc chains.
// GEMM: rg=t&3 -> rows {rg+4rr}; cg=t>>2 -> col group.
// ---------------------------------------------------------------------------
template<int D>
__global__ __launch_bounds__(256, 8) void k_mlp(
        const float* __restrict__ x,
        const int* __restrict__ rowptr, const int* __restrict__ cdeg,
        const int* __restrict__ eid, const int* __restrict__ ecls,
        const int* __restrict__ ncls,
        const float* __restrict__ ed, const float* __restrict__ el,
        const float* __restrict__ wa, const float* __restrict__ ba,
        const float* __restrict__ wb, const float* __restrict__ bb,
        float* __restrict__ ybuf, float* __restrict__ st) {
    constexpr int LDW = D + 4;
    __shared__ float xs[16 * LDW];
    int t = threadIdx.x;
    int row0 = blockIdx.x * 16;
    int lane = t & 63, wv = t >> 6;

    // ---- staging: gather self + neighbors into xs
    if constexpr (D == 128) {
        bool lo = lane < 32;
        const float* tab = lo ? ed : el;
        int cofs = lane * 2 - (lo ? 0 : 64);
        for (int i = 0; i < 4; ++i) {
            int lr = wv * 4 + i, node = row0 + lr;
            float a0 = 0.f, a1 = 0.f, b0 = 0.f, b1 = 0.f;
            if (node < N_NODES) {
                int start = rowptr[node], n = cdeg[node];
                int scls = ncls[node];
                int d = lo ? (scls & 0xffff) : (scls >> 16);
                float2 v = *(const float2*)(tab + d * 64 + cofs);
                a0 = v.x; a1 = v.y;
                for (int j0 = 0; j0 < n; j0 += 64) {
                    int m = n - j0; if (m > 64) m = 64;
                    int clsv = (lane < m) ? ecls[start + j0 + lane] : 0;
                    int j = 0;
                    for (; j + 2 <= m; j += 2) {
                        int c0 = __shfl(clsv, j), c1 = __shfl(clsv, j + 1);
                        int d0 = lo ? (c0 & 0xffff) : (c0 >> 16);
                        int d1 = lo ? (c1 & 0xffff) : (c1 >> 16);
                        float2 v0 = *(const float2*)(tab + d0 * 64 + cofs);
                        float2 v1 = *(const float2*)(tab + d1 * 64 + cofs);
                        a0 += v0.x; a1 += v0.y; b0 += v1.x; b1 += v1.y;
                    }
                    if (j < m) {
                        int c0 = __shfl(clsv, j);
                        int d0 = lo ? (c0 & 0xffff) : (c0 >> 16);
                        float2 v0 = *(const float2*)(tab + d0 * 64 + cofs);
                        a0 += v0.x; a1 += v0.y;
                    }
                }
            }
            *(float2*)(xs + lr * LDW + lane * 2) = make_float2(a0 + b0, a1 + b1);
        }
    } else {
        for (int i = 0; i < 4; ++i) {
            int lr = wv * 4 + i, node = row0 + lr;
            float a0 = 0.f, a1 = 0.f, a2 = 0.f, a3 = 0.f;
            if (node < N_NODES) {
                int start = rowptr[node], n = cdeg[node];
                a0 = x[(size_t)node * 64 + lane];
                for (int j0 = 0; j0 < n; j0 += 64) {
                    int m = n - j0; if (m > 64) m = 64;
                    int ev = (lane < m) ? eid[start + j0 + lane] : 0;
                    int j = 0;
                    for (; j + 4 <= m; j += 4) {
                        int s0 = __shfl(ev, j),     s1 = __shfl(ev, j + 1);
                        int s2 = __shfl(ev, j + 2), s3 = __shfl(ev, j + 3);
                        a0 += x[(size_t)s0 * 64 + lane];
                        a1 += x[(size_t)s1 * 64 + lane];
                        a2 += x[(size_t)s2 * 64 + lane];
                        a3 += x[(size_t)s3 * 64 + lane];
                    }
                    for (; j < m; ++j) {
                        int s0 = __shfl(ev, j);
                        a0 += x[(size_t)s0 * 64 + lane];
                    }
                }
            }
            xs[lr * LDW + lane] = (a0 + a1) + (a2 + a3);
        }
    }
    __syncthreads();

    int rg = t & 3, cg = t >> 2;
    constexpr int C1 = D / 64;   // lin1 cols per thread (2 or 1)

    // ---- lin1 + lrelu
    float acc1[4][C1];
    #pragma unroll
    for (int cc = 0; cc < C1; ++cc) {
        float bv = ba[cg * C1 + cc];
        #pragma unroll
        for (int rr = 0; rr < 4; ++rr) acc1[rr][cc] = bv;
    }
    #pragma unroll 1
    for (int ks = 0; ks < D; ks += 4) {
        float4 xv[4];
        #pragma unroll
        for (int rr = 0; rr < 4; ++rr)
            xv[rr] = *(const float4*)(xs + (rg + 4 * rr) * LDW + ks);
        #pragma unroll
        for (int cc = 0; cc < C1; ++cc) {
            float4 wv4 = *(const float4*)(wa + (size_t)(cg * C1 + cc) * D + ks);
            #pragma unroll
            for (int rr = 0; rr < 4; ++rr)
                acc1[rr][cc] += xv[rr].x * wv4.x + xv[rr].y * wv4.y
                              + xv[rr].z * wv4.z + xv[rr].w * wv4.w;
        }
    }
    #pragma unroll
    for (int rr = 0; rr < 4; ++rr)
        #pragma unroll
        for (int cc = 0; cc < C1; ++cc) {
            float a = acc1[rr][cc];
            acc1[rr][cc] = a > 0.f ? a : SLOPE * a;
        }
    __syncthreads();              // all lin1 reads of xs done
    #pragma unroll
    for (int rr = 0; rr < 4; ++rr) {
        if constexpr (C1 == 2)
            *(float2*)(xs + (rg + 4 * rr) * LDW + cg * 2) =
                make_float2(acc1[rr][0], acc1[rr][1]);
        else
            xs[(rg + 4 * rr) * LDW + cg] = acc1[rr][0];
    }
    __syncthreads();              // h tile visible

    // ---- lin2: 64 outputs, 1 col/thread (j = cg)
    float acc2[4];
    {
        float bv = bb[cg];
        #pragma unroll
        for (int rr = 0; rr < 4; ++rr) acc2[rr] = bv;
    }
    #pragma unroll 1
    for (int ks = 0; ks < D; ks += 4) {
        float4 xv[4];
        #pragma unroll
        for (int rr = 0; rr < 4; ++rr)
            xv[rr] = *(const float4*)(xs + (rg + 4 * rr) * LDW + ks);
        float4 wv4 = *(const float4*)(wb + (size_t)cg * D + ks);
        #pragma unroll
        for (int rr = 0; rr < 4; ++rr)
            acc2[rr] += xv[rr].x * wv4.x + xv[rr].y * wv4.y
                      + xv[rr].z * wv4.z + xv[rr].w * wv4.w;
    }
    // write ybuf + BN stats
    float ps = 0.f, pq = 0.f;
    #pragma unroll
    for (int rr = 0; rr < 4; ++rr) {
        int gr = row0 + rg + 4 * rr;
        bool ok = gr < N_NODES;
        if (ok) ybuf[(size_t)gr * 64 + cg] = acc2[rr];
        float a = ok ? acc2[rr] : 0.f;
        ps += a; pq += a * a;
    }
    ps += __shfl_down(ps, 2, 4); pq += __shfl_down(pq, 2, 4);
    ps += __shfl_down(ps, 1, 4); pq += __shfl_down(pq, 1, 4);
    if (rg == 0) {
        atomicAdd(&st[cg], ps);
        atomicAdd(&st[64 + cg], pq);
    }
}

// ---------------------------------------------------------------------------
// K4: x_out = lrelu(y*scale + shift); scale/shift computed inline from stats
// ---------------------------------------------------------------------------
__global__ void k_bn_apply(const float* __restrict__ y, const float* __restrict__ st,
                           const float* __restrict__ gw, const float* __restrict__ gb,
                           float* __restrict__ xo) {
    __shared__ float sc[64], sh[64];
    int t = threadIdx.x;
    if (t < 64) {
        float m = st[t] * (1.0f / N_NODES);
        float v = st[64 + t] * (1.0f / N_NODES) - m * m;
        float s = gw[t] * rsqrtf(v + BN_EPS);
        sc[t] = s; sh[t] = gb[t] - m * s;
    }
    __syncthreads();
    int idx = blockIdx.x * blockDim.x + t;
    if (idx >= N_NODES * 64) return;
    int c = idx & 63;
    float v = y[idx] * sc[c] + sh[c];
    xo[idx] = v > 0.f ? v : SLOPE * v;
}

// ---------------------------------------------------------------------------
// K5: fc1 over concat [x0|x1|x2|x3] (K=320), 32-row tiles, 4x2 reg tile
// ---------------------------------------------------------------------------
template<int SD>
__device__ __forceinline__ void fc1_seg(const float* __restrict__ xp, int row0, int t,
        int rg, int cg, float* xs, const float* __restrict__ w, float (&acc)[4][2]) {
    constexpr int LDW = SD + 4;
    constexpr int C4 = SD / 4;
    __syncthreads();  // previous segment's xs reads done
    for (int i4 = t; i4 < 32 * C4; i4 += 256) {
        int rr = i4 / C4, c4 = (i4 % C4) * 4;
        int g = row0 + rr;
        float4 v = (g < N_NODES) ? *(const float4*)(xp + (size_t)g * SD + c4)
                                 : make_float4(0.f, 0.f, 0.f, 0.f);
        *(float4*)(xs + rr * LDW + c4) = v;
    }
    __syncthreads();
    #pragma unroll 1
    for (int ks = 0; ks < SD; ks += 4) {
        float4 xv[4];
        #pragma unroll
        for (int rr = 0; rr < 4; ++rr)
            xv[rr] = *(const float4*)(xs + (rg + 8 * rr) * LDW + ks);
        #pragma unroll
        for (int cc = 0; cc < 2; ++cc) {
            float4 wv = *(const float4*)(w + (size_t)(cg * 2 + cc) * 320 + ks);
            #pragma unroll
            for (int rr = 0; rr < 4; ++rr)
                acc[rr][cc] += xv[rr].x * wv.x + xv[rr].y * wv.y
                             + xv[rr].z * wv.z + xv[rr].w * wv.w;
        }
    }
}

__global__ __launch_bounds__(256, 6) void k_fc1(
        const float* __restrict__ x0, const float* __restrict__ x1,
        const float* __restrict__ x2, const float* __restrict__ x3,
        const float* __restrict__ w, const float* __restrict__ b,
        float* __restrict__ ybuf, float* __restrict__ st) {
    __shared__ float xs[32 * 132];
    int t = threadIdx.x, rg = t & 7, cg = t >> 3;
    int row0 = blockIdx.x * 32;
    float acc[4][2];
    #pragma unroll
    for (int cc = 0; cc < 2; ++cc) {
        float bv = b[cg * 2 + cc];
        #pragma unroll
        for (int rr = 0; rr < 4; ++rr) acc[rr][cc] = bv;
    }
    fc1_seg<128>(x0, row0, t, rg, cg, xs, w + 0,   acc);
    fc1_seg<64> (x1, row0, t, rg, cg, xs, w + 128, acc);
    fc1_seg<64> (x2, row0, t, rg, cg, xs, w + 192, acc);
    fc1_seg<64> (x3, row0, t, rg, cg, xs, w + 256, acc);

    float ps[2] = {0.f, 0.f}, pq[2] = {0.f, 0.f};
    #pragma unroll
    for (int rr = 0; rr < 4; ++rr) {
        int gr = row0 + rg + 8 * rr;
        bool ok = gr < N_NODES;
        if (ok)
            *(float2*)(ybuf + (size_t)gr * 64 + cg * 2) = make_float2(acc[rr][0], acc[rr][1]);
        #pragma unroll
        for (int cc = 0; cc < 2; ++cc) {
            float a = ok ? acc[rr][cc] : 0.f;
            ps[cc] += a; pq[cc] += a * a;
        }
    }
    #pragma unroll
    for (int o = 4; o; o >>= 1)
        #pragma unroll
        for (int cc = 0; cc < 2; ++cc) {
            ps[cc] += __shfl_down(ps[cc], o, 8);
            pq[cc] += __shfl_down(pq[cc], o, 8);
        }
    if (rg == 0) {
        #pragma unroll
        for (int cc = 0; cc < 2; ++cc) {
            atomicAdd(&st[cg * 2 + cc], ps[cc]);
            atomicAdd(&st[64 + cg * 2 + cc], pq[cc]);
        }
    }
}

// ---------------------------------------------------------------------------
// K6: out = sigmoid( fc2_w . lrelu(bn(y)) + fc2_b ); bn from stats inline
// ---------------------------------------------------------------------------
__global__ void k_final(const float* __restrict__ y, const float* __restrict__ st,
                        const float* __restrict__ gw, const float* __restrict__ gb,
                        const float* __restrict__ w2, const float* __restrict__ b2,
                        float* __restrict__ out) {
    __shared__ float sc[64], sh[64], w[64];
    int t = threadIdx.x;
    if (t < 64) {
        float m = st[t] * (1.0f / N_NODES);
        float v = st[64 + t] * (1.0f / N_NODES) - m * m;
        float s = gw[t] * rsqrtf(v + BN_EPS);
        sc[t] = s; sh[t] = gb[t] - m * s; w[t] = w2[t];
    }
    __syncthreads();
    int i = blockIdx.x * blockDim.x + t;
    if (i >= N_NODES) return;
    float z = b2[0];
    const float* row = y + (size_t)i * 64;
    #pragma unroll
    for (int c = 0; c < 64; c += 4) {
        float4 v4 = *(const float4*)(row + c);
        float v;
        v = v4.x * sc[c]   + sh[c];   v = v > 0.f ? v : SLOPE * v; z += v * w[c];
        v = v4.y * sc[c+1] + sh[c+1]; v = v > 0.f ? v : SLOPE * v; z += v * w[c+1];
        v = v4.z * sc[c+2] + sh[c+2]; v = v > 0.f ? v : SLOPE * v; z += v * w[c+2];
        v = v4.w * sc[c+3] + sh[c+3]; v = v > 0.f ? v : SLOPE * v; z += v * w[c+3];
    }
    out[i] = 1.f / (1.f + __expf(-z));
}

// ---------------------------------------------------------------------------
extern "C" void kernel_launch(void* const* d_in, const int* in_sizes, int n_in,
                              void* d_out, int out_size, void* d_ws, size_t ws_size,
                              hipStream_t stream) {
    const float* emb_deg = (const float*)d_in[0];
    const float* emb_lab = (const float*)d_in[1];
    const float* wA[3]  = {(const float*)d_in[2],  (const float*)d_in[8],  (const float*)d_in[14]};
    const float* bA[3]  = {(const float*)d_in[3],  (const float*)d_in[9],  (const float*)d_in[15]};
    const float* wB[3]  = {(const float*)d_in[4],  (const float*)d_in[10], (const float*)d_in[16]};
    const float* bB[3]  = {(const float*)d_in[5],  (const float*)d_in[11], (const float*)d_in[17]};
    const float* bnw[3] = {(const float*)d_in[6],  (const float*)d_in[12], (const float*)d_in[18]};
    const float* bnb[3] = {(const float*)d_in[7],  (const float*)d_in[13], (const float*)d_in[19]};
    const float* fc1_w  = (const float*)d_in[20];
    const float* fc1_b  = (const float*)d_in[21];
    const float* fcbn_w = (const float*)d_in[22];
    const float* fcbn_b = (const float*)d_in[23];
    const float* fc2_w  = (const float*)d_in[24];
    const float* fc2_b  = (const float*)d_in[25];
    const int* node_deg = (const int*)d_in[26];
    const int* node_lab = (const int*)d_in[27];
    const int* src = (const int*)d_in[28];
    const int* dst = src + E_EDGES;
    float* out = (float*)d_out;

    // workspace layout
    float* ws  = (float*)d_ws;
    float* x0  = ws;                               // N*128
    float* x1  = x0  + (size_t)N_NODES * 128;      // N*64
    float* x2  = x1  + (size_t)N_NODES * 64;       // N*64
    float* x3  = x2  + (size_t)N_NODES * 64;       // N*64
    float* ybf = x3  + (size_t)N_NODES * 64;       // N*64
    float* stat = ybf + (size_t)N_NODES * 64;      // 4 layers x 128 floats
    int* cdeg   = (int*)(stat + 512);              // N (memset with stat)
    int* rowptr = cdeg + N_NODES;                  // N
    int* wptr   = rowptr + N_NODES;                // N
    int* ncls   = wptr + N_NODES;                  // N
    int* eid    = ncls + N_NODES;                  // E
    int* ecls   = eid + E_EDGES;                   // E

    const int RB = (N_NODES + 15) / 16;            // 3125 row-tile blocks
    const int FB = (N_NODES + 31) / 32;            // 1563 fc1 blocks
    const int GB = (N_NODES * 64 + 255) / 256;     // 12500 elementwise blocks
    const int EB = (E_EDGES + 255) / 256;          // 3125 edge blocks
    const int NB = (N_NODES + 255) / 256;          // 196 node blocks

    // one memset: stats (512 floats) + cdeg (N ints), contiguous
    hipMemsetAsync(stat, 0, (512 + N_NODES) * sizeof(float), stream);

    k_build_x0<<<GB, 256, 0, stream>>>(emb_deg, emb_lab, node_deg, node_lab, x0);
    k_cls<<<NB, 256, 0, stream>>>(node_deg, node_lab, ncls);

    // ---- CSR build (per launch; identical work every call)
    k_deg<<<EB, 256, 0, stream>>>(dst, cdeg);
    k_scan<<<1, 1024, 0, stream>>>(cdeg, rowptr, wptr);
    k_fill<<<EB, 256, 0, stream>>>(src, dst, ncls, wptr, eid, ecls);

    // ---- 3 GIN layers (gather fused into MLP staging)
    float* xin[4] = {x0, x1, x2, x3};
    for (int l = 0; l < 3; ++l) {
        float* st = stat + l * 128;
        if (l == 0)
            k_mlp<128><<<RB, 256, 0, stream>>>(xin[l], rowptr, cdeg, eid, ecls, ncls,
                emb_deg, emb_lab, wA[l], bA[l], wB[l], bB[l], ybf, st);
        else
            k_mlp<64><<<RB, 256, 0, stream>>>(xin[l], rowptr, cdeg, eid, ecls, ncls,
                emb_deg, emb_lab, wA[l], bA[l], wB[l], bB[l], ybf, st);
        k_bn_apply<<<GB, 256, 0, stream>>>(ybf, st, bnw[l], bnb[l], xin[l + 1]);
    }

    k_fc1<<<FB, 256, 0, stream>>>(x0, x1, x2, x3, fc1_w, fc1_b, ybf, stat + 384);
    k_final<<<NB, 256, 0, stream>>>(ybf, stat + 384, fcbn_w, fcbn_b,
                                    fc2_w, fc2_b, out);
}

// Round 8
// 676.396 us; speedup vs baseline: 10.8687x; 1.1744x over previous
//
#include <hip/hip_runtime.h>

// Problem constants (fixed by reference)
#define N_NODES 50000
#define E_EDGES 800000
#define BN_EPS 1e-5f
#define SLOPE 0.01f

#define SCAN_CHUNK 2048
#define SCAN_BLOCKS ((N_NODES + SCAN_CHUNK - 1) / SCAN_CHUNK)   // 25

// All float tensors are fp32; integer tensors int32; output fp32[N].

// ---------------------------------------------------------------------------
// K0: x0[n] = concat(emb_deg[deg[n]], emb_lab[lab[n]])  (needed for fc1)
// ---------------------------------------------------------------------------
__global__ void k_build_x0(const float* __restrict__ ed, const float* __restrict__ el,
                           const int* __restrict__ nd, const int* __restrict__ nl,
                           float* __restrict__ x0) {
    int idx = blockIdx.x * blockDim.x + threadIdx.x;  // N*32 float2 slots
    if (idx >= N_NODES * 32) return;
    int n = idx >> 5, c2 = idx & 31;
    const float2* edr = (const float2*)(ed + nd[n] * 64);
    const float2* elr = (const float2*)(el + nl[n] * 64);
    float2* o = (float2*)(x0 + (size_t)n * 128);
    o[c2]      = edr[c2];
    o[32 + c2] = elr[c2];
}

// K-cls: packed class per node
__global__ void k_cls(const int* __restrict__ nd, const int* __restrict__ nl,
                      int* __restrict__ ncls) {
    int n = blockIdx.x * blockDim.x + threadIdx.x;
    if (n < N_NODES) ncls[n] = nd[n] | (nl[n] << 16);
}

// ---------------------------------------------------------------------------
// CSR build: degree histogram -> hierarchical exclusive scan -> bucket fill
// ---------------------------------------------------------------------------
__global__ void k_deg(const int* __restrict__ dst, int* __restrict__ deg) {
    int e = blockIdx.x * blockDim.x + threadIdx.x;
    if (e >= E_EDGES) return;
    atomicAdd(&deg[dst[e]], 1);
}

// phase A: per-block (2048-elem) sums
__global__ __launch_bounds__(256) void k_scan_a(const int* __restrict__ deg,
                                                int* __restrict__ bsum) {
    __shared__ int ws[4];
    int t = threadIdx.x, b = blockIdx.x;
    int base = b * SCAN_CHUNK + t * 8;
    int s = 0;
    #pragma unroll
    for (int i = 0; i < 8; ++i) {
        int idx = base + i;
        if (idx < N_NODES) s += deg[idx];
    }
    #pragma unroll
    for (int o = 32; o; o >>= 1) s += __shfl_down(s, o);
    if ((t & 63) == 0) ws[t >> 6] = s;
    __syncthreads();
    if (t == 0) bsum[b] = ws[0] + ws[1] + ws[2] + ws[3];
}

// phase B: exclusive scan of 25 block sums (one wave)
__global__ void k_scan_b(const int* __restrict__ bsum, int* __restrict__ bofs) {
    int t = threadIdx.x;  // 64 threads
    int v = (t < SCAN_BLOCKS) ? bsum[t] : 0;
    int inc = v;
    #pragma unroll
    for (int o = 1; o < 32; o <<= 1) {
        int u = __shfl_up(inc, o, 32);
        if ((t & 31) >= o) inc += u;
    }
    if (t < SCAN_BLOCKS) bofs[t] = inc - v;
}

// phase C: rescan locally, add block offset, write rowptr & wptr
__global__ __launch_bounds__(256) void k_scan_c(const int* __restrict__ deg,
        const int* __restrict__ bofs, int* __restrict__ rowptr, int* __restrict__ wptr) {
    __shared__ int part[256];
    int t = threadIdx.x, b = blockIdx.x;
    int base = b * SCAN_CHUNK + t * 8;
    int vals[8];
    int s = 0;
    #pragma unroll
    for (int i = 0; i < 8; ++i) {
        int idx = base + i;
        vals[i] = (idx < N_NODES) ? deg[idx] : 0;
        s += vals[i];
    }
    part[t] = s;
    __syncthreads();
    #pragma unroll
    for (int off = 1; off < 256; off <<= 1) {
        int v = (t >= off) ? part[t - off] : 0;
        __syncthreads();
        part[t] += v;
        __syncthreads();
    }
    int run = bofs[b] + part[t] - s;   // exclusive prefix for this thread
    #pragma unroll
    for (int i = 0; i < 8; ++i) {
        int idx = base + i;
        if (idx < N_NODES) {
            rowptr[idx] = run;
            wptr[idx]   = run;
            run += vals[i];
        }
    }
}

__global__ void k_fill(const int* __restrict__ src, const int* __restrict__ dst,
                       const int* __restrict__ ncls,
                       int* __restrict__ wptr, int* __restrict__ eid,
                       int* __restrict__ ecls) {
    int e = blockIdx.x * blockDim.x + threadIdx.x;
    if (e >= E_EDGES) return;
    int s = src[e];
    int pos = atomicAdd(&wptr[dst[e]], 1);
    eid[pos]  = s;
    ecls[pos] = ncls[s];
}

// ---------------------------------------------------------------------------
// K2: fused gather + GIN MLP. Tile = 16 rows, 256 threads (4 waves), each
// wave stages 4 nodes. D=128 (layer 0): rows from the 80-row emb dictionary
// (L1-resident) via packed classes. D=64: batched eids + 8 acc chains.
// GEMM: rg=t&3 -> rows {rg+4rr}; cg=t>>2 -> col group.
// ---------------------------------------------------------------------------
template<int D>
__global__ __launch_bounds__(256, 8) void k_mlp(
        const float* __restrict__ x,
        const int* __restrict__ rowptr, const int* __restrict__ cdeg,
        const int* __restrict__ eid, const int* __restrict__ ecls,
        const int* __restrict__ ncls,
        const float* __restrict__ ed, const float* __restrict__ el,
        const float* __restrict__ wa, const float* __restrict__ ba,
        const float* __restrict__ wb, const float* __restrict__ bb,
        float* __restrict__ ybuf, float* __restrict__ st) {
    constexpr int LDW = D + 4;
    __shared__ float xs[16 * LDW];
    int t = threadIdx.x;
    int row0 = blockIdx.x * 16;
    int lane = t & 63, wv = t >> 6;

    // ---- staging: gather self + neighbors into xs
    if constexpr (D == 128) {
        bool lo = lane < 32;
        const float* tab = lo ? ed : el;
        int cofs = lane * 2 - (lo ? 0 : 64);
        for (int i = 0; i < 4; ++i) {
            int lr = wv * 4 + i, node = row0 + lr;
            float ax[4] = {0.f, 0.f, 0.f, 0.f}, ay[4] = {0.f, 0.f, 0.f, 0.f};
            if (node < N_NODES) {
                int start = rowptr[node], n = cdeg[node];
                int scls = ncls[node];
                int d = lo ? (scls & 0xffff) : (scls >> 16);
                float2 v = *(const float2*)(tab + d * 64 + cofs);
                ax[0] = v.x; ay[0] = v.y;
                for (int j0 = 0; j0 < n; j0 += 64) {
                    int m = n - j0; if (m > 64) m = 64;
                    int clsv = (lane < m) ? ecls[start + j0 + lane] : 0;
                    int j = 0;
                    for (; j + 4 <= m; j += 4) {
                        #pragma unroll
                        for (int q = 0; q < 4; ++q) {
                            int cq = __shfl(clsv, j + q);
                            int dq = lo ? (cq & 0xffff) : (cq >> 16);
                            float2 vq = *(const float2*)(tab + dq * 64 + cofs);
                            ax[q] += vq.x; ay[q] += vq.y;
                        }
                    }
                    for (; j < m; ++j) {
                        int c0 = __shfl(clsv, j);
                        int d0 = lo ? (c0 & 0xffff) : (c0 >> 16);
                        float2 v0 = *(const float2*)(tab + d0 * 64 + cofs);
                        ax[0] += v0.x; ay[0] += v0.y;
                    }
                }
            }
            *(float2*)(xs + lr * LDW + lane * 2) =
                make_float2((ax[0] + ax[1]) + (ax[2] + ax[3]),
                            (ay[0] + ay[1]) + (ay[2] + ay[3]));
        }
    } else {
        for (int i = 0; i < 4; ++i) {
            int lr = wv * 4 + i, node = row0 + lr;
            float a[8] = {0.f, 0.f, 0.f, 0.f, 0.f, 0.f, 0.f, 0.f};
            if (node < N_NODES) {
                int start = rowptr[node], n = cdeg[node];
                a[0] = x[(size_t)node * 64 + lane];
                for (int j0 = 0; j0 < n; j0 += 64) {
                    int m = n - j0; if (m > 64) m = 64;
                    int ev = (lane < m) ? eid[start + j0 + lane] : 0;
                    int j = 0;
                    for (; j + 8 <= m; j += 8) {
                        #pragma unroll
                        for (int q = 0; q < 8; ++q) {
                            int sq = __shfl(ev, j + q);
                            a[q] += x[(size_t)sq * 64 + lane];
                        }
                    }
                    for (; j < m; ++j) {
                        int s0 = __shfl(ev, j);
                        a[0] += x[(size_t)s0 * 64 + lane];
                    }
                }
            }
            xs[lr * LDW + lane] = ((a[0] + a[1]) + (a[2] + a[3]))
                                + ((a[4] + a[5]) + (a[6] + a[7]));
        }
    }
    __syncthreads();

    int rg = t & 3, cg = t >> 2;
    constexpr int C1 = D / 64;   // lin1 cols per thread (2 or 1)

    // ---- lin1 + lrelu
    float acc1[4][C1];
    #pragma unroll
    for (int cc = 0; cc < C1; ++cc) {
        float bv = ba[cg * C1 + cc];
        #pragma unroll
        for (int rr = 0; rr < 4; ++rr) acc1[rr][cc] = bv;
    }
    #pragma unroll 1
    for (int ks = 0; ks < D; ks += 4) {
        float4 xv[4];
        #pragma unroll
        for (int rr = 0; rr < 4; ++rr)
            xv[rr] = *(const float4*)(xs + (rg + 4 * rr) * LDW + ks);
        #pragma unroll
        for (int cc = 0; cc < C1; ++cc) {
            float4 wv4 = *(const float4*)(wa + (size_t)(cg * C1 + cc) * D + ks);
            #pragma unroll
            for (int rr = 0; rr < 4; ++rr)
                acc1[rr][cc] += xv[rr].x * wv4.x + xv[rr].y * wv4.y
                              + xv[rr].z * wv4.z + xv[rr].w * wv4.w;
        }
    }
    #pragma unroll
    for (int rr = 0; rr < 4; ++rr)
        #pragma unroll
        for (int cc = 0; cc < C1; ++cc) {
            float a = acc1[rr][cc];
            acc1[rr][cc] = a > 0.f ? a : SLOPE * a;
        }
    __syncthreads();              // all lin1 reads of xs done
    #pragma unroll
    for (int rr = 0; rr < 4; ++rr) {
        if constexpr (C1 == 2)
            *(float2*)(xs + (rg + 4 * rr) * LDW + cg * 2) =
                make_float2(acc1[rr][0], acc1[rr][1]);
        else
            xs[(rg + 4 * rr) * LDW + cg] = acc1[rr][0];
    }
    __syncthreads();              // h tile visible

    // ---- lin2: 64 outputs, 1 col/thread (j = cg)
    float acc2[4];
    {
        float bv = bb[cg];
        #pragma unroll
        for (int rr = 0; rr < 4; ++rr) acc2[rr] = bv;
    }
    #pragma unroll 1
    for (int ks = 0; ks < D; ks += 4) {
        float4 xv[4];
        #pragma unroll
        for (int rr = 0; rr < 4; ++rr)
            xv[rr] = *(const float4*)(xs + (rg + 4 * rr) * LDW + ks);
        float4 wv4 = *(const float4*)(wb + (size_t)cg * D + ks);
        #pragma unroll
        for (int rr = 0; rr < 4; ++rr)
            acc2[rr] += xv[rr].x * wv4.x + xv[rr].y * wv4.y
                      + xv[rr].z * wv4.z + xv[rr].w * wv4.w;
    }
    // write ybuf + BN stats
    float ps = 0.f, pq = 0.f;
    #pragma unroll
    for (int rr = 0; rr < 4; ++rr) {
        int gr = row0 + rg + 4 * rr;
        bool ok = gr < N_NODES;
        if (ok) ybuf[(size_t)gr * 64 + cg] = acc2[rr];
        float a = ok ? acc2[rr] : 0.f;
        ps += a; pq += a * a;
    }
    ps += __shfl_down(ps, 2, 4); pq += __shfl_down(pq, 2, 4);
    ps += __shfl_down(ps, 1, 4); pq += __shfl_down(pq, 1, 4);
    if (rg == 0) {
        atomicAdd(&st[cg], ps);
        atomicAdd(&st[64 + cg], pq);
    }
}

// ---------------------------------------------------------------------------
// K4: x_out = lrelu(y*scale + shift); scale/shift from stats; float4/thread
// ---------------------------------------------------------------------------
__global__ void k_bn_apply(const float* __restrict__ y, const float* __restrict__ st,
                           const float* __restrict__ gw, const float* __restrict__ gb,
                           float* __restrict__ xo) {
    __shared__ float sc[64], sh[64];
    int t = threadIdx.x;
    if (t < 64) {
        float m = st[t] * (1.0f / N_NODES);
        float v = st[64 + t] * (1.0f / N_NODES) - m * m;
        float s = gw[t] * rsqrtf(v + BN_EPS);
        sc[t] = s; sh[t] = gb[t] - m * s;
    }
    __syncthreads();
    int idx = blockIdx.x * blockDim.x + t;    // N*16 float4 slots
    if (idx >= N_NODES * 16) return;
    int c4 = (idx & 15) * 4;
    float4 v4 = *(const float4*)(y + (size_t)idx * 4);
    float4 o;
    o.x = v4.x * sc[c4]     + sh[c4];     o.x = o.x > 0.f ? o.x : SLOPE * o.x;
    o.y = v4.y * sc[c4 + 1] + sh[c4 + 1]; o.y = o.y > 0.f ? o.y : SLOPE * o.y;
    o.z = v4.z * sc[c4 + 2] + sh[c4 + 2]; o.z = o.z > 0.f ? o.z : SLOPE * o.z;
    o.w = v4.w * sc[c4 + 3] + sh[c4 + 3]; o.w = o.w > 0.f ? o.w : SLOPE * o.w;
    *(float4*)(xo + (size_t)idx * 4) = o;
}

// ---------------------------------------------------------------------------
// K5: fc1 over concat [x0|x1|x2|x3] (K=320), 32-row tiles, 4x2 reg tile
// ---------------------------------------------------------------------------
template<int SD>
__device__ __forceinline__ void fc1_seg(const float* __restrict__ xp, int row0, int t,
        int rg, int cg, float* xs, const float* __restrict__ w, float (&acc)[4][2]) {
    constexpr int LDW = SD + 4;
    constexpr int C4 = SD / 4;
    __syncthreads();  // previous segment's xs reads done
    for (int i4 = t; i4 < 32 * C4; i4 += 256) {
        int rr = i4 / C4, c4 = (i4 % C4) * 4;
        int g = row0 + rr;
        float4 v = (g < N_NODES) ? *(const float4*)(xp + (size_t)g * SD + c4)
                                 : make_float4(0.f, 0.f, 0.f, 0.f);
        *(float4*)(xs + rr * LDW + c4) = v;
    }
    __syncthreads();
    #pragma unroll 1
    for (int ks = 0; ks < SD; ks += 4) {
        float4 xv[4];
        #pragma unroll
        for (int rr = 0; rr < 4; ++rr)
            xv[rr] = *(const float4*)(xs + (rg + 8 * rr) * LDW + ks);
        #pragma unroll
        for (int cc = 0; cc < 2; ++cc) {
            float4 wv = *(const float4*)(w + (size_t)(cg * 2 + cc) * 320 + ks);
            #pragma unroll
            for (int rr = 0; rr < 4; ++rr)
                acc[rr][cc] += xv[rr].x * wv.x + xv[rr].y * wv.y
                             + xv[rr].z * wv.z + xv[rr].w * wv.w;
        }
    }
}

__global__ __launch_bounds__(256, 6) void k_fc1(
        const float* __restrict__ x0, const float* __restrict__ x1,
        const float* __restrict__ x2, const float* __restrict__ x3,
        const float* __restrict__ w, const float* __restrict__ b,
        float* __restrict__ ybuf, float* __restrict__ st) {
    __shared__ float xs[32 * 132];
    int t = threadIdx.x, rg = t & 7, cg = t >> 3;
    int row0 = blockIdx.x * 32;
    float acc[4][2];
    #pragma unroll
    for (int cc = 0; cc < 2; ++cc) {
        float bv = b[cg * 2 + cc];
        #pragma unroll
        for (int rr = 0; rr < 4; ++rr) acc[rr][cc] = bv;
    }
    fc1_seg<128>(x0, row0, t, rg, cg, xs, w + 0,   acc);
    fc1_seg<64> (x1, row0, t, rg, cg, xs, w + 128, acc);
    fc1_seg<64> (x2, row0, t, rg, cg, xs, w + 192, acc);
    fc1_seg<64> (x3, row0, t, rg, cg, xs, w + 256, acc);

    float ps[2] = {0.f, 0.f}, pq[2] = {0.f, 0.f};
    #pragma unroll
    for (int rr = 0; rr < 4; ++rr) {
        int gr = row0 + rg + 8 * rr;
        bool ok = gr < N_NODES;
        if (ok)
            *(float2*)(ybuf + (size_t)gr * 64 + cg * 2) = make_float2(acc[rr][0], acc[rr][1]);
        #pragma unroll
        for (int cc = 0; cc < 2; ++cc) {
            float a = ok ? acc[rr][cc] : 0.f;
            ps[cc] += a; pq[cc] += a * a;
        }
    }
    #pragma unroll
    for (int o = 4; o; o >>= 1)
        #pragma unroll
        for (int cc = 0; cc < 2; ++cc) {
            ps[cc] += __shfl_down(ps[cc], o, 8);
            pq[cc] += __shfl_down(pq[cc], o, 8);
        }
    if (rg == 0) {
        #pragma unroll
        for (int cc = 0; cc < 2; ++cc) {
            atomicAdd(&st[cg * 2 + cc], ps[cc]);
            atomicAdd(&st[64 + cg * 2 + cc], pq[cc]);
        }
    }
}

// ---------------------------------------------------------------------------
// K6: out = sigmoid( fc2_w . lrelu(bn(y)) + fc2_b ); bn from stats inline
// ---------------------------------------------------------------------------
__global__ void k_final(const float* __restrict__ y, const float* __restrict__ st,
                        const float* __restrict__ gw, const float* __restrict__ gb,
                        const float* __restrict__ w2, const float* __restrict__ b2,
                        float* __restrict__ out) {
    __shared__ float sc[64], sh[64], w[64];
    int t = threadIdx.x;
    if (t < 64) {
        float m = st[t] * (1.0f / N_NODES);
        float v = st[64 + t] * (1.0f / N_NODES) - m * m;
        float s = gw[t] * rsqrtf(v + BN_EPS);
        sc[t] = s; sh[t] = gb[t] - m * s; w[t] = w2[t];
    }
    __syncthreads();
    int i = blockIdx.x * blockDim.x + t;
    if (i >= N_NODES) return;
    float z = b2[0];
    const float* row = y + (size_t)i * 64;
    #pragma unroll
    for (int c = 0; c < 64; c += 4) {
        float4 v4 = *(const float4*)(row + c);
        float v;
        v = v4.x * sc[c]   + sh[c];   v = v > 0.f ? v : SLOPE * v; z += v * w[c];
        v = v4.y * sc[c+1] + sh[c+1]; v = v > 0.f ? v : SLOPE * v; z += v * w[c+1];
        v = v4.z * sc[c+2] + sh[c+2]; v = v > 0.f ? v : SLOPE * v; z += v * w[c+2];
        v = v4.w * sc[c+3] + sh[c+3]; v = v > 0.f ? v : SLOPE * v; z += v * w[c+3];
    }
    out[i] = 1.f / (1.f + __expf(-z));
}

// ---------------------------------------------------------------------------
extern "C" void kernel_launch(void* const* d_in, const int* in_sizes, int n_in,
                              void* d_out, int out_size, void* d_ws, size_t ws_size,
                              hipStream_t stream) {
    const float* emb_deg = (const float*)d_in[0];
    const float* emb_lab = (const float*)d_in[1];
    const float* wA[3]  = {(const float*)d_in[2],  (const float*)d_in[8],  (const float*)d_in[14]};
    const float* bA[3]  = {(const float*)d_in[3],  (const float*)d_in[9],  (const float*)d_in[15]};
    const float* wB[3]  = {(const float*)d_in[4],  (const float*)d_in[10], (const float*)d_in[16]};
    const float* bB[3]  = {(const float*)d_in[5],  (const float*)d_in[11], (const float*)d_in[17]};
    const float* bnw[3] = {(const float*)d_in[6],  (const float*)d_in[12], (const float*)d_in[18]};
    const float* bnb[3] = {(const float*)d_in[7],  (const float*)d_in[13], (const float*)d_in[19]};
    const float* fc1_w  = (const float*)d_in[20];
    const float* fc1_b  = (const float*)d_in[21];
    const float* fcbn_w = (const float*)d_in[22];
    const float* fcbn_b = (const float*)d_in[23];
    const float* fc2_w  = (const float*)d_in[24];
    const float* fc2_b  = (const float*)d_in[25];
    const int* node_deg = (const int*)d_in[26];
    const int* node_lab = (const int*)d_in[27];
    const int* src = (const int*)d_in[28];
    const int* dst = src + E_EDGES;
    float* out = (float*)d_out;

    // workspace layout
    float* ws  = (float*)d_ws;
    float* x0  = ws;                               // N*128
    float* x1  = x0  + (size_t)N_NODES * 128;      // N*64
    float* x2  = x1  + (size_t)N_NODES * 64;       // N*64
    float* x3  = x2  + (size_t)N_NODES * 64;       // N*64
    float* ybf = x3  + (size_t)N_NODES * 64;       // N*64
    float* stat = ybf + (size_t)N_NODES * 64;      // 4 layers x 128 floats
    int* cdeg   = (int*)(stat + 512);              // N (memset with stat)
    int* rowptr = cdeg + N_NODES;                  // N
    int* wptr   = rowptr + N_NODES;                // N
    int* ncls   = wptr + N_NODES;                  // N
    int* bsum   = ncls + N_NODES;                  // SCAN_BLOCKS
    int* bofs   = bsum + SCAN_BLOCKS;              // SCAN_BLOCKS
    int* eid    = bofs + SCAN_BLOCKS;              // E
    int* ecls   = eid + E_EDGES;                   // E

    const int RB = (N_NODES + 15) / 16;            // 3125 row-tile blocks
    const int FB = (N_NODES + 31) / 32;            // 1563 fc1 blocks
    const int VB = (N_NODES * 16 + 255) / 256;     // 3125 float4 elementwise blocks
    const int HB = (N_NODES * 32 + 255) / 256;     // 6250 float2 build blocks
    const int EB = (E_EDGES + 255) / 256;          // 3125 edge blocks
    const int NB = (N_NODES + 255) / 256;          // 196 node blocks

    // one memset: stats (512 floats) + cdeg (N ints), contiguous
    hipMemsetAsync(stat, 0, (512 + N_NODES) * sizeof(float), stream);

    k_build_x0<<<HB, 256, 0, stream>>>(emb_deg, emb_lab, node_deg, node_lab, x0);
    k_cls<<<NB, 256, 0, stream>>>(node_deg, node_lab, ncls);

    // ---- CSR build (per launch; identical work every call)
    k_deg<<<EB, 256, 0, stream>>>(dst, cdeg);
    k_scan_a<<<SCAN_BLOCKS, 256, 0, stream>>>(cdeg, bsum);
    k_scan_b<<<1, 64, 0, stream>>>(bsum, bofs);
    k_scan_c<<<SCAN_BLOCKS, 256, 0, stream>>>(cdeg, bofs, rowptr, wptr);
    k_fill<<<EB, 256, 0, stream>>>(src, dst, ncls, wptr, eid, ecls);

    // ---- 3 GIN layers (gather fused into MLP staging)
    float* xin[4] = {x0, x1, x2, x3};
    for (int l = 0; l < 3; ++l) {
        float* st = stat + l * 128;
        if (l == 0)
            k_mlp<128><<<RB, 256, 0, stream>>>(xin[l], rowptr, cdeg, eid, ecls, ncls,
                emb_deg, emb_lab, wA[l], bA[l], wB[l], bB[l], ybf, st);
        else
            k_mlp<64><<<RB, 256, 0, stream>>>(xin[l], rowptr, cdeg, eid, ecls, ncls,
                emb_deg, emb_lab, wA[l], bA[l], wB[l], bB[l], ybf, st);
        k_bn_apply<<<VB, 256, 0, stream>>>(ybf, st, bnw[l], bnb[l], xin[l + 1]);
    }

    k_fc1<<<FB, 256, 0, stream>>>(x0, x1, x2, x3, fc1_w, fc1_b, ybf, stat + 384);
    k_final<<<NB, 256, 0, stream>>>(ybf, stat + 384, fcbn_w, fcbn_b,
                                    fc2_w, fc2_b, out);
}

// Round 9
// 413.449 us; speedup vs baseline: 17.7811x; 1.6360x over previous
//
#include <hip/hip_runtime.h>

// Problem constants (fixed by reference)
#define N_NODES 50000
#define E_EDGES 800000
#define BN_EPS 1e-5f
#define SLOPE 0.01f

#define SCAN_CHUNK 2048
#define SCAN_BLOCKS ((N_NODES + SCAN_CHUNK - 1) / SCAN_CHUNK)   // 25
#define STAT_SHARDS 32

typedef unsigned short ushort_t;
typedef unsigned int uint_t;
typedef short short8 __attribute__((ext_vector_type(8)));
typedef float floatx4 __attribute__((ext_vector_type(4)));

__device__ __forceinline__ float b2f(ushort_t v) {
    return __uint_as_float(((uint_t)v) << 16);
}
__device__ __forceinline__ ushort_t f2b(float f) {   // round-to-nearest-even
    uint_t u = __float_as_uint(f);
    return (ushort_t)((u + 0x7fffu + ((u >> 16) & 1u)) >> 16);
}
__device__ __forceinline__ uint_t pack2(float a, float b) {
    return (uint_t)f2b(a) | ((uint_t)f2b(b) << 16);
}

// bf16 weight buffer offsets (elements)
#define OWA0 0
#define OWB0 16384
#define OWA1 24576
#define OWB1 28672
#define OWA2 32768
#define OWB2 36864
#define OFC1 40960
#define WTOT 61440

// ---------------------------------------------------------------------------
// K-cvt: convert all GEMM weights fp32 -> bf16 into one contiguous buffer
// ---------------------------------------------------------------------------
__global__ void k_cvt(const float* __restrict__ wa0, const float* __restrict__ wb0,
                      const float* __restrict__ wa1, const float* __restrict__ wb1,
                      const float* __restrict__ wa2, const float* __restrict__ wb2,
                      const float* __restrict__ fc1w, ushort_t* __restrict__ dst) {
    int i = blockIdx.x * blockDim.x + threadIdx.x;
    if (i >= WTOT) return;
    float v;
    if      (i < OWB0) v = wa0[i];
    else if (i < OWA1) v = wb0[i - OWB0];
    else if (i < OWB1) v = wa1[i - OWA1];
    else if (i < OWA2) v = wb1[i - OWB1];
    else if (i < OWB2) v = wa2[i - OWA2];
    else if (i < OFC1) v = wb2[i - OWB2];
    else               v = fc1w[i - OFC1];
    dst[i] = f2b(v);
}

// ---------------------------------------------------------------------------
// K0: x0 (bf16) = concat(emb_deg[deg[n]], emb_lab[lab[n]])
// ---------------------------------------------------------------------------
__global__ void k_build_x0(const float* __restrict__ ed, const float* __restrict__ el,
                           const int* __restrict__ nd, const int* __restrict__ nl,
                           uint_t* __restrict__ x0u) {
    int idx = blockIdx.x * blockDim.x + threadIdx.x;  // N*64 uint slots
    if (idx >= N_NODES * 64) return;
    int n = idx >> 6, c = idx & 63;
    float2 v = (c < 32) ? *(const float2*)(ed + nd[n] * 64 + c * 2)
                        : *(const float2*)(el + nl[n] * 64 + (c - 32) * 2);
    x0u[(size_t)n * 64 + c] = pack2(v.x, v.y);
}

// K-cls: packed class per node
__global__ void k_cls(const int* __restrict__ nd, const int* __restrict__ nl,
                      int* __restrict__ ncls) {
    int n = blockIdx.x * blockDim.x + threadIdx.x;
    if (n < N_NODES) ncls[n] = nd[n] | (nl[n] << 16);
}

// ---------------------------------------------------------------------------
// CSR build: degree histogram -> hierarchical exclusive scan -> bucket fill
// ---------------------------------------------------------------------------
__global__ void k_deg(const int* __restrict__ dst, int* __restrict__ deg) {
    int e = blockIdx.x * blockDim.x + threadIdx.x;
    if (e >= E_EDGES) return;
    atomicAdd(&deg[dst[e]], 1);
}

__global__ __launch_bounds__(256) void k_scan_a(const int* __restrict__ deg,
                                                int* __restrict__ bsum) {
    __shared__ int wsum[4];
    int t = threadIdx.x, b = blockIdx.x;
    int base = b * SCAN_CHUNK + t * 8;
    int s = 0;
    #pragma unroll
    for (int i = 0; i < 8; ++i) {
        int idx = base + i;
        if (idx < N_NODES) s += deg[idx];
    }
    #pragma unroll
    for (int o = 32; o; o >>= 1) s += __shfl_down(s, o);
    if ((t & 63) == 0) wsum[t >> 6] = s;
    __syncthreads();
    if (t == 0) bsum[b] = wsum[0] + wsum[1] + wsum[2] + wsum[3];
}

__global__ void k_scan_b(const int* __restrict__ bsum, int* __restrict__ bofs) {
    int t = threadIdx.x;  // 64
    int v = (t < SCAN_BLOCKS) ? bsum[t] : 0;
    int inc = v;
    #pragma unroll
    for (int o = 1; o < 32; o <<= 1) {
        int u = __shfl_up(inc, o, 32);
        if ((t & 31) >= o) inc += u;
    }
    if (t < SCAN_BLOCKS) bofs[t] = inc - v;
}

__global__ __launch_bounds__(256) void k_scan_c(const int* __restrict__ deg,
        const int* __restrict__ bofs, int* __restrict__ rowptr, int* __restrict__ wptr) {
    __shared__ int part[256];
    int t = threadIdx.x, b = blockIdx.x;
    int base = b * SCAN_CHUNK + t * 8;
    int vals[8];
    int s = 0;
    #pragma unroll
    for (int i = 0; i < 8; ++i) {
        int idx = base + i;
        vals[i] = (idx < N_NODES) ? deg[idx] : 0;
        s += vals[i];
    }
    part[t] = s;
    __syncthreads();
    #pragma unroll
    for (int off = 1; off < 256; off <<= 1) {
        int v = (t >= off) ? part[t - off] : 0;
        __syncthreads();
        part[t] += v;
        __syncthreads();
    }
    int run = bofs[b] + part[t] - s;
    #pragma unroll
    for (int i = 0; i < 8; ++i) {
        int idx = base + i;
        if (idx < N_NODES) {
            rowptr[idx] = run;
            wptr[idx]   = run;
            run += vals[i];
        }
    }
}

__global__ void k_fill(const int* __restrict__ src, const int* __restrict__ dst,
                       const int* __restrict__ ncls,
                       int* __restrict__ wptr, int* __restrict__ eid,
                       int* __restrict__ ecls) {
    int e = blockIdx.x * blockDim.x + threadIdx.x;
    if (e >= E_EDGES) return;
    int s = src[e];
    int pos = atomicAdd(&wptr[dst[e]], 1);
    eid[pos]  = s;
    ecls[pos] = ncls[s];
}

// ---------------------------------------------------------------------------
// K2: fused gather + GIN MLP, MFMA GEMM (bf16 in, fp32 acc).
// Tile = 16 rows (nodes). Staging as before (fp32 accumulate, bf16 to LDS).
// lin1: A=xs[16xD], B=waB[N1xD] row-major; lin2: A=hs, B=wbB[64xD].
// Frag maps (verified m89/m120): A[m=lane&15][k=quad*8+j]; B[k][n=lane&15];
// C/D col=lane&15, row=quad*4+reg.
// ---------------------------------------------------------------------------
template<int D>
__global__ __launch_bounds__(256, 8) void k_mlp(
        const ushort_t* __restrict__ xb,
        const int* __restrict__ rowptr, const int* __restrict__ cdeg,
        const int* __restrict__ eid, const int* __restrict__ ecls,
        const int* __restrict__ ncls,
        const float* __restrict__ ed, const float* __restrict__ el,
        const ushort_t* __restrict__ waB, const float* __restrict__ ba,
        const ushort_t* __restrict__ wbB, const float* __restrict__ bb,
        float* __restrict__ ybuf, float* __restrict__ stat_l) {
    constexpr int LDWB = D + 8;          // ushort stride; mult of 8 (16B align)
    __shared__ ushort_t xs[16 * LDWB];
    __shared__ ushort_t hs[16 * LDWB];
    int t = threadIdx.x;
    int row0 = blockIdx.x * 16;
    int lane = t & 63, wv = t >> 6;

    // ---- staging: gather self + neighbors -> bf16 LDS
    if constexpr (D == 128) {
        bool lo = lane < 32;
        const float* tab = lo ? ed : el;
        int cofs = lane * 2 - (lo ? 0 : 64);
        uint_t* xsu = (uint_t*)xs;
        for (int i = 0; i < 4; ++i) {
            int lr = wv * 4 + i, node = row0 + lr;
            float ax[4] = {0.f, 0.f, 0.f, 0.f}, ay[4] = {0.f, 0.f, 0.f, 0.f};
            if (node < N_NODES) {
                int start = rowptr[node], n = cdeg[node];
                int scls = ncls[node];
                int d = lo ? (scls & 0xffff) : (scls >> 16);
                float2 v = *(const float2*)(tab + d * 64 + cofs);
                ax[0] = v.x; ay[0] = v.y;
                for (int j0 = 0; j0 < n; j0 += 64) {
                    int m = n - j0; if (m > 64) m = 64;
                    int clsv = (lane < m) ? ecls[start + j0 + lane] : 0;
                    int j = 0;
                    for (; j + 4 <= m; j += 4) {
                        #pragma unroll
                        for (int q = 0; q < 4; ++q) {
                            int cq = __shfl(clsv, j + q);
                            int dq = lo ? (cq & 0xffff) : (cq >> 16);
                            float2 vq = *(const float2*)(tab + dq * 64 + cofs);
                            ax[q] += vq.x; ay[q] += vq.y;
                        }
                    }
                    for (; j < m; ++j) {
                        int c0 = __shfl(clsv, j);
                        int d0 = lo ? (c0 & 0xffff) : (c0 >> 16);
                        float2 v0 = *(const float2*)(tab + d0 * 64 + cofs);
                        ax[0] += v0.x; ay[0] += v0.y;
                    }
                }
            }
            xsu[lr * (LDWB / 2) + lane] =
                pack2((ax[0] + ax[1]) + (ax[2] + ax[3]),
                      (ay[0] + ay[1]) + (ay[2] + ay[3]));
        }
    } else {
        for (int i = 0; i < 4; ++i) {
            int lr = wv * 4 + i, node = row0 + lr;
            float a[8] = {0.f, 0.f, 0.f, 0.f, 0.f, 0.f, 0.f, 0.f};
            if (node < N_NODES) {
                int start = rowptr[node], n = cdeg[node];
                a[0] = b2f(xb[(size_t)node * 64 + lane]);
                for (int j0 = 0; j0 < n; j0 += 64) {
                    int m = n - j0; if (m > 64) m = 64;
                    int ev = (lane < m) ? eid[start + j0 + lane] : 0;
                    int j = 0;
                    for (; j + 8 <= m; j += 8) {
                        #pragma unroll
                        for (int q = 0; q < 8; ++q) {
                            int sq = __shfl(ev, j + q);
                            a[q] += b2f(xb[(size_t)sq * 64 + lane]);
                        }
                    }
                    for (; j < m; ++j) {
                        int s0 = __shfl(ev, j);
                        a[0] += b2f(xb[(size_t)s0 * 64 + lane]);
                    }
                }
            }
            xs[lr * LDWB + lane] = f2b(((a[0] + a[1]) + (a[2] + a[3]))
                                     + ((a[4] + a[5]) + (a[6] + a[7])));
        }
    }
    __syncthreads();

    int m = lane & 15, quad = lane >> 4;
    constexpr int NKS = D / 32;          // K-chunks
    constexpr int NG1 = D / 64;          // lin1 col-groups per wave (2 or 1)

    // ---- lin1 (MFMA) + lrelu -> hs
    {
        floatx4 acc[NG1];
        #pragma unroll
        for (int g = 0; g < NG1; ++g) acc[g] = (floatx4){0.f, 0.f, 0.f, 0.f};
        #pragma unroll
        for (int ks = 0; ks < NKS; ++ks) {
            short8 af = *(const short8*)(xs + m * LDWB + ks * 32 + quad * 8);
            #pragma unroll
            for (int g = 0; g < NG1; ++g) {
                int col = (wv * NG1 + g) * 16 + m;
                short8 bf = *(const short8*)(waB + (size_t)col * D + ks * 32 + quad * 8);
                acc[g] = __builtin_amdgcn_mfma_f32_16x16x32_bf16(af, bf, acc[g], 0, 0, 0);
            }
        }
        #pragma unroll
        for (int g = 0; g < NG1; ++g) {
            int col = (wv * NG1 + g) * 16 + m;
            float bias = ba[col];
            #pragma unroll
            for (int r = 0; r < 4; ++r) {
                float v = acc[g][r] + bias;
                v = v > 0.f ? v : SLOPE * v;
                hs[(quad * 4 + r) * LDWB + col] = f2b(v);
            }
        }
    }
    __syncthreads();

    // ---- lin2 (MFMA): 64 outputs, group = wv
    {
        floatx4 acc = (floatx4){0.f, 0.f, 0.f, 0.f};
        int col = wv * 16 + m;
        #pragma unroll
        for (int ks = 0; ks < NKS; ++ks) {
            short8 af = *(const short8*)(hs + m * LDWB + ks * 32 + quad * 8);
            short8 bf = *(const short8*)(wbB + (size_t)col * D + ks * 32 + quad * 8);
            acc = __builtin_amdgcn_mfma_f32_16x16x32_bf16(af, bf, acc, 0, 0, 0);
        }
        float bias = bb[col];
        float ps = 0.f, pq = 0.f;
        #pragma unroll
        for (int r = 0; r < 4; ++r) {
            int node = row0 + quad * 4 + r;
            float v = acc[r] + bias;
            if (node < N_NODES) ybuf[(size_t)node * 64 + col] = v;
            else v = 0.f;
            ps += v; pq += v * v;
        }
        ps += __shfl_xor(ps, 16); pq += __shfl_xor(pq, 16);
        ps += __shfl_xor(ps, 32); pq += __shfl_xor(pq, 32);
        if (quad == 0) {
            float* st = stat_l + (blockIdx.x & (STAT_SHARDS - 1)) * 128;
            atomicAdd(&st[col], ps);
            atomicAdd(&st[64 + col], pq);
        }
    }
}

// ---------------------------------------------------------------------------
// K4: x_out(bf16) = lrelu(y*scale + shift); stats summed over shards
// ---------------------------------------------------------------------------
__global__ void k_bn_apply(const float* __restrict__ y, const float* __restrict__ stat_l,
                           const float* __restrict__ gw, const float* __restrict__ gb,
                           uint_t* __restrict__ xo) {
    __shared__ float sc[64], sh[64];
    int t = threadIdx.x;
    if (t < 64) {
        float s0 = 0.f, q0 = 0.f;
        #pragma unroll
        for (int j = 0; j < STAT_SHARDS; ++j) {
            s0 += stat_l[j * 128 + t];
            q0 += stat_l[j * 128 + 64 + t];
        }
        float mmm = s0 * (1.0f / N_NODES);
        float var = q0 * (1.0f / N_NODES) - mmm * mmm;
        float s = gw[t] * rsqrtf(var + BN_EPS);
        sc[t] = s; sh[t] = gb[t] - mmm * s;
    }
    __syncthreads();
    int idx = blockIdx.x * blockDim.x + t;    // N*16 float4 slots
    if (idx >= N_NODES * 16) return;
    int c4 = (idx & 15) * 4;
    float4 v4 = *(const float4*)(y + (size_t)idx * 4);
    float o0 = v4.x * sc[c4]     + sh[c4];     o0 = o0 > 0.f ? o0 : SLOPE * o0;
    float o1 = v4.y * sc[c4 + 1] + sh[c4 + 1]; o1 = o1 > 0.f ? o1 : SLOPE * o1;
    float o2 = v4.z * sc[c4 + 2] + sh[c4 + 2]; o2 = o2 > 0.f ? o2 : SLOPE * o2;
    float o3 = v4.w * sc[c4 + 3] + sh[c4 + 3]; o3 = o3 > 0.f ? o3 : SLOPE * o3;
    xo[(size_t)idx * 2]     = pack2(o0, o1);
    xo[(size_t)idx * 2 + 1] = pack2(o2, o3);
}

// ---------------------------------------------------------------------------
// K5: fc1 (MFMA) over bf16 concat [x0|x1|x2|x3], K=320, N=64, 16-row tiles
// ---------------------------------------------------------------------------
__global__ __launch_bounds__(256, 8) void k_fc1(
        const uint_t* __restrict__ x0u, const uint_t* __restrict__ x1u,
        const uint_t* __restrict__ x2u, const uint_t* __restrict__ x3u,
        const ushort_t* __restrict__ wB, const float* __restrict__ b,
        float* __restrict__ ybuf, float* __restrict__ stat_l) {
    constexpr int LDWB = 328;            // ushort stride (320+8), /2=164 uints
    __shared__ ushort_t xs[16 * LDWB];
    uint_t* xsu = (uint_t*)xs;
    int t = threadIdx.x;
    int row0 = blockIdx.x * 16;

    for (int i = t; i < 16 * 160; i += 256) {
        int row = i / 160, c = i % 160;
        int g = row0 + row;
        uint_t v = 0;
        if (g < N_NODES) {
            if      (c < 64)  v = x0u[(size_t)g * 64 + c];
            else if (c < 96)  v = x1u[(size_t)g * 32 + (c - 64)];
            else if (c < 128) v = x2u[(size_t)g * 32 + (c - 96)];
            else              v = x3u[(size_t)g * 32 + (c - 128)];
        }
        xsu[row * 164 + c] = v;
    }
    __syncthreads();

    int lane = t & 63, wv = t >> 6;
    int m = lane & 15, quad = lane >> 4;
    int col = wv * 16 + m;
    floatx4 acc = (floatx4){0.f, 0.f, 0.f, 0.f};
    #pragma unroll
    for (int ks = 0; ks < 10; ++ks) {
        short8 af = *(const short8*)(xs + m * LDWB + ks * 32 + quad * 8);
        short8 bf = *(const short8*)(wB + (size_t)col * 320 + ks * 32 + quad * 8);
        acc = __builtin_amdgcn_mfma_f32_16x16x32_bf16(af, bf, acc, 0, 0, 0);
    }
    float bias = b[col];
    float ps = 0.f, pq = 0.f;
    #pragma unroll
    for (int r = 0; r < 4; ++r) {
        int node = row0 + quad * 4 + r;
        float v = acc[r] + bias;
        if (node < N_NODES) ybuf[(size_t)node * 64 + col] = v;
        else v = 0.f;
        ps += v; pq += v * v;
    }
    ps += __shfl_xor(ps, 16); pq += __shfl_xor(pq, 16);
    ps += __shfl_xor(ps, 32); pq += __shfl_xor(pq, 32);
    if (quad == 0) {
        float* st = stat_l + (blockIdx.x & (STAT_SHARDS - 1)) * 128;
        atomicAdd(&st[col], ps);
        atomicAdd(&st[64 + col], pq);
    }
}

// ---------------------------------------------------------------------------
// K6: out = sigmoid( fc2_w . lrelu(bn(y)) + fc2_b )
// ---------------------------------------------------------------------------
__global__ void k_final(const float* __restrict__ y, const float* __restrict__ stat_l,
                        const float* __restrict__ gw, const float* __restrict__ gb,
                        const float* __restrict__ w2, const float* __restrict__ b2,
                        float* __restrict__ out) {
    __shared__ float sc[64], sh[64], w[64];
    int t = threadIdx.x;
    if (t < 64) {
        float s0 = 0.f, q0 = 0.f;
        #pragma unroll
        for (int j = 0; j < STAT_SHARDS; ++j) {
            s0 += stat_l[j * 128 + t];
            q0 += stat_l[j * 128 + 64 + t];
        }
        float mmm = s0 * (1.0f / N_NODES);
        float var = q0 * (1.0f / N_NODES) - mmm * mmm;
        float s = gw[t] * rsqrtf(var + BN_EPS);
        sc[t] = s; sh[t] = gb[t] - mmm * s; w[t] = w2[t];
    }
    __syncthreads();
    int i = blockIdx.x * blockDim.x + t;
    if (i >= N_NODES) return;
    float z = b2[0];
    const float* row = y + (size_t)i * 64;
    #pragma unroll
    for (int c = 0; c < 64; c += 4) {
        float4 v4 = *(const float4*)(row + c);
        float v;
        v = v4.x * sc[c]   + sh[c];   v = v > 0.f ? v : SLOPE * v; z += v * w[c];
        v = v4.y * sc[c+1] + sh[c+1]; v = v > 0.f ? v : SLOPE * v; z += v * w[c+1];
        v = v4.z * sc[c+2] + sh[c+2]; v = v > 0.f ? v : SLOPE * v; z += v * w[c+2];
        v = v4.w * sc[c+3] + sh[c+3]; v = v > 0.f ? v : SLOPE * v; z += v * w[c+3];
    }
    out[i] = 1.f / (1.f + __expf(-z));
}

// ---------------------------------------------------------------------------
extern "C" void kernel_launch(void* const* d_in, const int* in_sizes, int n_in,
                              void* d_out, int out_size, void* d_ws, size_t ws_size,
                              hipStream_t stream) {
    const float* emb_deg = (const float*)d_in[0];
    const float* emb_lab = (const float*)d_in[1];
    const float* wA[3]  = {(const float*)d_in[2],  (const float*)d_in[8],  (const float*)d_in[14]};
    const float* bA[3]  = {(const float*)d_in[3],  (const float*)d_in[9],  (const float*)d_in[15]};
    const float* wB[3]  = {(const float*)d_in[4],  (const float*)d_in[10], (const float*)d_in[16]};
    const float* bB[3]  = {(const float*)d_in[5],  (const float*)d_in[11], (const float*)d_in[17]};
    const float* bnw[3] = {(const float*)d_in[6],  (const float*)d_in[12], (const float*)d_in[18]};
    const float* bnb[3] = {(const float*)d_in[7],  (const float*)d_in[13], (const float*)d_in[19]};
    const float* fc1_w  = (const float*)d_in[20];
    const float* fc1_b  = (const float*)d_in[21];
    const float* fcbn_w = (const float*)d_in[22];
    const float* fcbn_b = (const float*)d_in[23];
    const float* fc2_w  = (const float*)d_in[24];
    const float* fc2_b  = (const float*)d_in[25];
    const int* node_deg = (const int*)d_in[26];
    const int* node_lab = (const int*)d_in[27];
    const int* src = (const int*)d_in[28];
    const int* dst = src + E_EDGES;
    float* out = (float*)d_out;

    // workspace layout
    float* ws   = (float*)d_ws;
    float* ybf  = ws;                                  // N*64 fp32
    float* stat = ybf + (size_t)N_NODES * 64;          // 4 * 32 * 128 floats
    uint_t* x0u = (uint_t*)(stat + 4 * STAT_SHARDS * 128);  // N*64 uints (bf16 x2)
    uint_t* x1u = x0u + (size_t)N_NODES * 64;          // N*32
    uint_t* x2u = x1u + (size_t)N_NODES * 32;          // N*32
    uint_t* x3u = x2u + (size_t)N_NODES * 32;          // N*32
    ushort_t* wbf = (ushort_t*)(x3u + (size_t)N_NODES * 32);  // WTOT bf16
    int* cdeg   = (int*)(wbf + WTOT);                  // N (memset w/ stat? no - separate)
    int* rowptr = cdeg + N_NODES;
    int* wptr   = rowptr + N_NODES;
    int* ncls   = wptr + N_NODES;
    int* bsum   = ncls + N_NODES;
    int* bofs   = bsum + SCAN_BLOCKS;
    int* eid    = bofs + SCAN_BLOCKS;                  // E
    int* ecls   = eid + E_EDGES;                       // E

    const int RB = (N_NODES + 15) / 16;            // 3125 row-tile blocks
    const int VB = (N_NODES * 16 + 255) / 256;     // 3125 float4 elementwise blocks
    const int HB = (N_NODES * 64 + 255) / 256;     // 12500 build-x0 blocks
    const int EB = (E_EDGES + 255) / 256;          // 3125 edge blocks
    const int NB = (N_NODES + 255) / 256;          // 196 node blocks

    hipMemsetAsync(stat, 0, (size_t)(4 * STAT_SHARDS * 128) * sizeof(float), stream);
    hipMemsetAsync(cdeg, 0, (size_t)N_NODES * sizeof(int), stream);

    k_cvt<<<(WTOT + 255) / 256, 256, 0, stream>>>(wA[0], wB[0], wA[1], wB[1],
                                                  wA[2], wB[2], fc1_w, wbf);
    k_build_x0<<<HB, 256, 0, stream>>>(emb_deg, emb_lab, node_deg, node_lab, x0u);
    k_cls<<<NB, 256, 0, stream>>>(node_deg, node_lab, ncls);

    // ---- CSR build
    k_deg<<<EB, 256, 0, stream>>>(dst, cdeg);
    k_scan_a<<<SCAN_BLOCKS, 256, 0, stream>>>(cdeg, bsum);
    k_scan_b<<<1, 64, 0, stream>>>(bsum, bofs);
    k_scan_c<<<SCAN_BLOCKS, 256, 0, stream>>>(cdeg, bofs, rowptr, wptr);
    k_fill<<<EB, 256, 0, stream>>>(src, dst, ncls, wptr, eid, ecls);

    // ---- 3 GIN layers
    const ushort_t* waOfs[3] = {wbf + OWA0, wbf + OWA1, wbf + OWA2};
    const ushort_t* wbOfs[3] = {wbf + OWB0, wbf + OWB1, wbf + OWB2};
    uint_t* xin[4] = {x0u, x1u, x2u, x3u};
    for (int l = 0; l < 3; ++l) {
        float* st = stat + l * STAT_SHARDS * 128;
        if (l == 0)
            k_mlp<128><<<RB, 256, 0, stream>>>((const ushort_t*)xin[l], rowptr, cdeg,
                eid, ecls, ncls, emb_deg, emb_lab,
                waOfs[l], bA[l], wbOfs[l], bB[l], ybf, st);
        else
            k_mlp<64><<<RB, 256, 0, stream>>>((const ushort_t*)xin[l], rowptr, cdeg,
                eid, ecls, ncls, emb_deg, emb_lab,
                waOfs[l], bA[l], wbOfs[l], bB[l], ybf, st);
        k_bn_apply<<<VB, 256, 0, stream>>>(ybf, st, bnw[l], bnb[l], xin[l + 1]);
    }

    float* stf = stat + 3 * STAT_SHARDS * 128;
    k_fc1<<<RB, 256, 0, stream>>>(x0u, x1u, x2u, x3u, wbf + OFC1, fc1_b, ybf, stf);
    k_final<<<NB, 256, 0, stream>>>(ybf, stf, fcbn_w, fcbn_b, fc2_w, fc2_b, out);
}

// Round 10
// 376.356 us; speedup vs baseline: 19.5336x; 1.0986x over previous
//
#include <hip/hip_runtime.h>

// Problem constants (fixed by reference)
#define N_NODES 50000
#define E_EDGES 800000
#define BN_EPS 1e-5f
#define SLOPE 0.01f

#define SCAN_CHUNK 2048
#define SCAN_BLOCKS ((N_NODES + SCAN_CHUNK - 1) / SCAN_CHUNK)   // 25
#define STAT_SHARDS 32

typedef unsigned short ushort_t;
typedef unsigned int uint_t;
typedef short short8 __attribute__((ext_vector_type(8)));
typedef float floatx4 __attribute__((ext_vector_type(4)));

__device__ __forceinline__ float b2f(ushort_t v) {
    return __uint_as_float(((uint_t)v) << 16);
}
__device__ __forceinline__ float ulo(uint_t v) {   // low bf16 of packed pair
    return __uint_as_float(v << 16);
}
__device__ __forceinline__ float uhi(uint_t v) {   // high bf16 of packed pair
    return __uint_as_float(v & 0xffff0000u);
}
__device__ __forceinline__ ushort_t f2b(float f) {   // round-to-nearest-even
    uint_t u = __float_as_uint(f);
    return (ushort_t)((u + 0x7fffu + ((u >> 16) & 1u)) >> 16);
}
__device__ __forceinline__ uint_t pack2(float a, float b) {
    return (uint_t)f2b(a) | ((uint_t)f2b(b) << 16);
}

// bf16 weight buffer offsets (elements)
#define OWA0 0
#define OWB0 16384
#define OWA1 24576
#define OWB1 28672
#define OWA2 32768
#define OWB2 36864
#define OFC1 40960
#define WTOT 61440

// ---------------------------------------------------------------------------
// K-cvt: convert all GEMM weights fp32 -> bf16 into one contiguous buffer
// ---------------------------------------------------------------------------
__global__ void k_cvt(const float* __restrict__ wa0, const float* __restrict__ wb0,
                      const float* __restrict__ wa1, const float* __restrict__ wb1,
                      const float* __restrict__ wa2, const float* __restrict__ wb2,
                      const float* __restrict__ fc1w, ushort_t* __restrict__ dst) {
    int i = blockIdx.x * blockDim.x + threadIdx.x;
    if (i >= WTOT) return;
    float v;
    if      (i < OWB0) v = wa0[i];
    else if (i < OWA1) v = wb0[i - OWB0];
    else if (i < OWB1) v = wa1[i - OWA1];
    else if (i < OWA2) v = wb1[i - OWB1];
    else if (i < OWB2) v = wa2[i - OWA2];
    else if (i < OFC1) v = wb2[i - OWB2];
    else               v = fc1w[i - OFC1];
    dst[i] = f2b(v);
}

// ---------------------------------------------------------------------------
// K0: x0 (bf16) = concat(emb_deg[deg[n]], emb_lab[lab[n]]); also write ncls
// ---------------------------------------------------------------------------
__global__ void k_build_x0(const float* __restrict__ ed, const float* __restrict__ el,
                           const int* __restrict__ nd, const int* __restrict__ nl,
                           uint_t* __restrict__ x0u, int* __restrict__ ncls) {
    int idx = blockIdx.x * blockDim.x + threadIdx.x;  // N*64 uint slots
    if (idx >= N_NODES * 64) return;
    int n = idx >> 6, c = idx & 63;
    int d = nd[n], l = nl[n];
    if (c == 0) ncls[n] = d | (l << 16);
    float2 v = (c < 32) ? *(const float2*)(ed + d * 64 + c * 2)
                        : *(const float2*)(el + l * 64 + (c - 32) * 2);
    x0u[(size_t)n * 64 + c] = pack2(v.x, v.y);
}

// ---------------------------------------------------------------------------
// CSR build: degree histogram -> hierarchical exclusive scan -> bucket fill
// ---------------------------------------------------------------------------
__global__ void k_deg(const int* __restrict__ dst, int* __restrict__ deg) {
    int e = blockIdx.x * blockDim.x + threadIdx.x;
    if (e >= E_EDGES) return;
    atomicAdd(&deg[dst[e]], 1);
}

__global__ __launch_bounds__(256) void k_scan_a(const int* __restrict__ deg,
                                                int* __restrict__ bsum) {
    __shared__ int wsum[4];
    int t = threadIdx.x, b = blockIdx.x;
    int base = b * SCAN_CHUNK + t * 8;
    int s = 0;
    #pragma unroll
    for (int i = 0; i < 8; ++i) {
        int idx = base + i;
        if (idx < N_NODES) s += deg[idx];
    }
    #pragma unroll
    for (int o = 32; o; o >>= 1) s += __shfl_down(s, o);
    if ((t & 63) == 0) wsum[t >> 6] = s;
    __syncthreads();
    if (t == 0) bsum[b] = wsum[0] + wsum[1] + wsum[2] + wsum[3];
}

__global__ void k_scan_b(const int* __restrict__ bsum, int* __restrict__ bofs) {
    int t = threadIdx.x;  // 64
    int v = (t < SCAN_BLOCKS) ? bsum[t] : 0;
    int inc = v;
    #pragma unroll
    for (int o = 1; o < 32; o <<= 1) {
        int u = __shfl_up(inc, o, 32);
        if ((t & 31) >= o) inc += u;
    }
    if (t < SCAN_BLOCKS) bofs[t] = inc - v;
}

__global__ __launch_bounds__(256) void k_scan_c(const int* __restrict__ deg,
        const int* __restrict__ bofs, int* __restrict__ rowptr, int* __restrict__ wptr) {
    __shared__ int part[256];
    int t = threadIdx.x, b = blockIdx.x;
    int base = b * SCAN_CHUNK + t * 8;
    int vals[8];
    int s = 0;
    #pragma unroll
    for (int i = 0; i < 8; ++i) {
        int idx = base + i;
        vals[i] = (idx < N_NODES) ? deg[idx] : 0;
        s += vals[i];
    }
    part[t] = s;
    __syncthreads();
    #pragma unroll
    for (int off = 1; off < 256; off <<= 1) {
        int v = (t >= off) ? part[t - off] : 0;
        __syncthreads();
        part[t] += v;
        __syncthreads();
    }
    int run = bofs[b] + part[t] - s;
    #pragma unroll
    for (int i = 0; i < 8; ++i) {
        int idx = base + i;
        if (idx < N_NODES) {
            rowptr[idx] = run;
            wptr[idx]   = run;
            run += vals[i];
        }
    }
}

__global__ void k_fill(const int* __restrict__ src, const int* __restrict__ dst,
                       const int* __restrict__ ncls,
                       int* __restrict__ wptr, int2* __restrict__ ebuf) {
    int e = blockIdx.x * blockDim.x + threadIdx.x;
    if (e >= E_EDGES) return;
    int s = src[e];
    int pos = atomicAdd(&wptr[dst[e]], 1);
    ebuf[pos] = make_int2(s, ncls[s]);   // one 8B scattered store
}

// ---------------------------------------------------------------------------
// K2: fused gather + GIN MLP, MFMA GEMM (bf16 in, fp32 acc).
// Tile = 16 rows. Staging: each wave processes 2 nodes concurrently (two
// 32-lane halves; __shfl width=32 broadcasts per half). D=128: float4/lane
// from the 80-row emb dictionary. D=64: bf16-pair/lane from x.
// ---------------------------------------------------------------------------
template<int D>
__global__ __launch_bounds__(256, 8) void k_mlp(
        const ushort_t* __restrict__ xb,
        const int* __restrict__ rowptr, const int* __restrict__ cdeg,
        const int2* __restrict__ ebuf, const int* __restrict__ ncls,
        const float* __restrict__ ed, const float* __restrict__ el,
        const ushort_t* __restrict__ waB, const float* __restrict__ ba,
        const ushort_t* __restrict__ wbB, const float* __restrict__ bb,
        float* __restrict__ ybuf, float* __restrict__ stat_l) {
    constexpr int LDWB = D + 8;          // ushort stride; mult of 8 (16B align)
    __shared__ ushort_t xs[16 * LDWB];
    __shared__ ushort_t hs[16 * LDWB];
    int t = threadIdx.x;
    int row0 = blockIdx.x * 16;
    int lane = t & 63, wv = t >> 6;
    int half = lane >> 5, hl = lane & 31;
    uint_t* xsu = (uint_t*)xs;

    // ---- staging: gather self + neighbors -> bf16 LDS (2 nodes per wave)
    if constexpr (D == 128) {
        bool lo = hl < 16;
        const float* tab = lo ? ed : el;
        int dcol = (lo ? hl : hl - 16) * 4;
        for (int i = 0; i < 2; ++i) {
            int lr = wv * 4 + i * 2 + half, node = row0 + lr;
            float ax = 0.f, ay = 0.f, az = 0.f, aw = 0.f;
            float bx = 0.f, by = 0.f, bz = 0.f, bw = 0.f;
            if (node < N_NODES) {
                int start = rowptr[node], n = cdeg[node];
                int scls = ncls[node];
                int d = lo ? (scls & 0xffff) : (scls >> 16);
                float4 v = *(const float4*)(tab + d * 64 + dcol);
                ax = v.x; ay = v.y; az = v.z; aw = v.w;
                for (int j0 = 0; j0 < n; j0 += 32) {
                    int m = n - j0; if (m > 32) m = 32;
                    int clsv = (hl < m) ? ebuf[start + j0 + hl].y : 0;
                    int j = 0;
                    for (; j + 2 <= m; j += 2) {
                        int c0 = __shfl(clsv, j, 32), c1 = __shfl(clsv, j + 1, 32);
                        int d0 = lo ? (c0 & 0xffff) : (c0 >> 16);
                        int d1 = lo ? (c1 & 0xffff) : (c1 >> 16);
                        float4 v0 = *(const float4*)(tab + d0 * 64 + dcol);
                        float4 v1 = *(const float4*)(tab + d1 * 64 + dcol);
                        ax += v0.x; ay += v0.y; az += v0.z; aw += v0.w;
                        bx += v1.x; by += v1.y; bz += v1.z; bw += v1.w;
                    }
                    if (j < m) {
                        int c0 = __shfl(clsv, j, 32);
                        int d0 = lo ? (c0 & 0xffff) : (c0 >> 16);
                        float4 v0 = *(const float4*)(tab + d0 * 64 + dcol);
                        ax += v0.x; ay += v0.y; az += v0.z; aw += v0.w;
                    }
                }
            }
            xsu[lr * (LDWB / 2) + hl * 2]     = pack2(ax + bx, ay + by);
            xsu[lr * (LDWB / 2) + hl * 2 + 1] = pack2(az + bz, aw + bw);
        }
    } else {
        const uint_t* xu = (const uint_t*)xb;     // row = 32 bf16-pairs
        for (int i = 0; i < 2; ++i) {
            int lr = wv * 4 + i * 2 + half, node = row0 + lr;
            float a0 = 0.f, a1 = 0.f, b0 = 0.f, b1 = 0.f;
            float c0f = 0.f, c1f = 0.f, d0f = 0.f, d1f = 0.f;
            if (node < N_NODES) {
                int start = rowptr[node], n = cdeg[node];
                uint_t sv = xu[(size_t)node * 32 + hl];
                a0 = ulo(sv); a1 = uhi(sv);
                for (int j0 = 0; j0 < n; j0 += 32) {
                    int m = n - j0; if (m > 32) m = 32;
                    int ev = (hl < m) ? ebuf[start + j0 + hl].x : 0;
                    int j = 0;
                    for (; j + 4 <= m; j += 4) {
                        int s0 = __shfl(ev, j, 32),     s1 = __shfl(ev, j + 1, 32);
                        int s2 = __shfl(ev, j + 2, 32), s3 = __shfl(ev, j + 3, 32);
                        uint_t v0 = xu[(size_t)s0 * 32 + hl];
                        uint_t v1 = xu[(size_t)s1 * 32 + hl];
                        uint_t v2 = xu[(size_t)s2 * 32 + hl];
                        uint_t v3 = xu[(size_t)s3 * 32 + hl];
                        a0 += ulo(v0); a1 += uhi(v0);
                        b0 += ulo(v1); b1 += uhi(v1);
                        c0f += ulo(v2); c1f += uhi(v2);
                        d0f += ulo(v3); d1f += uhi(v3);
                    }
                    for (; j < m; ++j) {
                        int s0 = __shfl(ev, j, 32);
                        uint_t v0 = xu[(size_t)s0 * 32 + hl];
                        a0 += ulo(v0); a1 += uhi(v0);
                    }
                }
            }
            xsu[lr * (LDWB / 2) + hl] = pack2((a0 + b0) + (c0f + d0f),
                                              (a1 + b1) + (c1f + d1f));
        }
    }
    __syncthreads();

    int m = lane & 15, quad = lane >> 4;
    constexpr int NKS = D / 32;          // K-chunks
    constexpr int NG1 = D / 64;          // lin1 col-groups per wave (2 or 1)

    // ---- lin1 (MFMA) + lrelu -> hs
    {
        floatx4 acc[NG1];
        #pragma unroll
        for (int g = 0; g < NG1; ++g) acc[g] = (floatx4){0.f, 0.f, 0.f, 0.f};
        #pragma unroll
        for (int ks = 0; ks < NKS; ++ks) {
            short8 af = *(const short8*)(xs + m * LDWB + ks * 32 + quad * 8);
            #pragma unroll
            for (int g = 0; g < NG1; ++g) {
                int col = (wv * NG1 + g) * 16 + m;
                short8 bf = *(const short8*)(waB + (size_t)col * D + ks * 32 + quad * 8);
                acc[g] = __builtin_amdgcn_mfma_f32_16x16x32_bf16(af, bf, acc[g], 0, 0, 0);
            }
        }
        #pragma unroll
        for (int g = 0; g < NG1; ++g) {
            int col = (wv * NG1 + g) * 16 + m;
            float bias = ba[col];
            #pragma unroll
            for (int r = 0; r < 4; ++r) {
                float v = acc[g][r] + bias;
                v = v > 0.f ? v : SLOPE * v;
                hs[(quad * 4 + r) * LDWB + col] = f2b(v);
            }
        }
    }
    __syncthreads();

    // ---- lin2 (MFMA): 64 outputs, group = wv
    {
        floatx4 acc = (floatx4){0.f, 0.f, 0.f, 0.f};
        int col = wv * 16 + m;
        #pragma unroll
        for (int ks = 0; ks < NKS; ++ks) {
            short8 af = *(const short8*)(hs + m * LDWB + ks * 32 + quad * 8);
            short8 bf = *(const short8*)(wbB + (size_t)col * D + ks * 32 + quad * 8);
            acc = __builtin_amdgcn_mfma_f32_16x16x32_bf16(af, bf, acc, 0, 0, 0);
        }
        float bias = bb[col];
        float ps = 0.f, pq = 0.f;
        #pragma unroll
        for (int r = 0; r < 4; ++r) {
            int node = row0 + quad * 4 + r;
            float v = acc[r] + bias;
            if (node < N_NODES) ybuf[(size_t)node * 64 + col] = v;
            else v = 0.f;
            ps += v; pq += v * v;
        }
        ps += __shfl_xor(ps, 16); pq += __shfl_xor(pq, 16);
        ps += __shfl_xor(ps, 32); pq += __shfl_xor(pq, 32);
        if (quad == 0) {
            float* st = stat_l + (blockIdx.x & (STAT_SHARDS - 1)) * 128;
            atomicAdd(&st[col], ps);
            atomicAdd(&st[64 + col], pq);
        }
    }
}

// ---------------------------------------------------------------------------
// K4: x_out(bf16) = lrelu(y*scale + shift); stats summed over shards
// ---------------------------------------------------------------------------
__global__ void k_bn_apply(const float* __restrict__ y, const float* __restrict__ stat_l,
                           const float* __restrict__ gw, const float* __restrict__ gb,
                           uint_t* __restrict__ xo) {
    __shared__ float sc[64], sh[64];
    int t = threadIdx.x;
    if (t < 64) {
        float s0 = 0.f, q0 = 0.f;
        #pragma unroll
        for (int j = 0; j < STAT_SHARDS; ++j) {
            s0 += stat_l[j * 128 + t];
            q0 += stat_l[j * 128 + 64 + t];
        }
        float mmm = s0 * (1.0f / N_NODES);
        float var = q0 * (1.0f / N_NODES) - mmm * mmm;
        float s = gw[t] * rsqrtf(var + BN_EPS);
        sc[t] = s; sh[t] = gb[t] - mmm * s;
    }
    __syncthreads();
    int idx = blockIdx.x * blockDim.x + t;    // N*16 float4 slots
    if (idx >= N_NODES * 16) return;
    int c4 = (idx & 15) * 4;
    float4 v4 = *(const float4*)(y + (size_t)idx * 4);
    float o0 = v4.x * sc[c4]     + sh[c4];     o0 = o0 > 0.f ? o0 : SLOPE * o0;
    float o1 = v4.y * sc[c4 + 1] + sh[c4 + 1]; o1 = o1 > 0.f ? o1 : SLOPE * o1;
    float o2 = v4.z * sc[c4 + 2] + sh[c4 + 2]; o2 = o2 > 0.f ? o2 : SLOPE * o2;
    float o3 = v4.w * sc[c4 + 3] + sh[c4 + 3]; o3 = o3 > 0.f ? o3 : SLOPE * o3;
    xo[(size_t)idx * 2]     = pack2(o0, o1);
    xo[(size_t)idx * 2 + 1] = pack2(o2, o3);
}

// ---------------------------------------------------------------------------
// K5: fc1 (MFMA) over bf16 concat [x0|x1|x2|x3], K=320, N=64, 16-row tiles
// ---------------------------------------------------------------------------
__global__ __launch_bounds__(256, 8) void k_fc1(
        const uint_t* __restrict__ x0u, const uint_t* __restrict__ x1u,
        const uint_t* __restrict__ x2u, const uint_t* __restrict__ x3u,
        const ushort_t* __restrict__ wB, const float* __restrict__ b,
        float* __restrict__ ybuf, float* __restrict__ stat_l) {
    constexpr int LDWB = 328;            // ushort stride (320+8), /2=164 uints
    __shared__ ushort_t xs[16 * LDWB];
    uint_t* xsu = (uint_t*)xs;
    int t = threadIdx.x;
    int row0 = blockIdx.x * 16;

    for (int i = t; i < 16 * 160; i += 256) {
        int row = i / 160, c = i % 160;
        int g = row0 + row;
        uint_t v = 0;
        if (g < N_NODES) {
            if      (c < 64)  v = x0u[(size_t)g * 64 + c];
            else if (c < 96)  v = x1u[(size_t)g * 32 + (c - 64)];
            else if (c < 128) v = x2u[(size_t)g * 32 + (c - 96)];
            else              v = x3u[(size_t)g * 32 + (c - 128)];
        }
        xsu[row * 164 + c] = v;
    }
    __syncthreads();

    int lane = t & 63, wv = t >> 6;
    int m = lane & 15, quad = lane >> 4;
    int col = wv * 16 + m;
    floatx4 acc = (floatx4){0.f, 0.f, 0.f, 0.f};
    #pragma unroll
    for (int ks = 0; ks < 10; ++ks) {
        short8 af = *(const short8*)(xs + m * LDWB + ks * 32 + quad * 8);
        short8 bf = *(const short8*)(wB + (size_t)col * 320 + ks * 32 + quad * 8);
        acc = __builtin_amdgcn_mfma_f32_16x16x32_bf16(af, bf, acc, 0, 0, 0);
    }
    float bias = b[col];
    float ps = 0.f, pq = 0.f;
    #pragma unroll
    for (int r = 0; r < 4; ++r) {
        int node = row0 + quad * 4 + r;
        float v = acc[r] + bias;
        if (node < N_NODES) ybuf[(size_t)node * 64 + col] = v;
        else v = 0.f;
        ps += v; pq += v * v;
    }
    ps += __shfl_xor(ps, 16); pq += __shfl_xor(pq, 16);
    ps += __shfl_xor(ps, 32); pq += __shfl_xor(pq, 32);
    if (quad == 0) {
        float* st = stat_l + (blockIdx.x & (STAT_SHARDS - 1)) * 128;
        atomicAdd(&st[col], ps);
        atomicAdd(&st[64 + col], pq);
    }
}

// ---------------------------------------------------------------------------
// K6: out = sigmoid( fc2_w . lrelu(bn(y)) + fc2_b )
// ---------------------------------------------------------------------------
__global__ void k_final(const float* __restrict__ y, const float* __restrict__ stat_l,
                        const float* __restrict__ gw, const float* __restrict__ gb,
                        const float* __restrict__ w2, const float* __restrict__ b2,
                        float* __restrict__ out) {
    __shared__ float sc[64], sh[64], w[64];
    int t = threadIdx.x;
    if (t < 64) {
        float s0 = 0.f, q0 = 0.f;
        #pragma unroll
        for (int j = 0; j < STAT_SHARDS; ++j) {
            s0 += stat_l[j * 128 + t];
            q0 += stat_l[j * 128 + 64 + t];
        }
        float mmm = s0 * (1.0f / N_NODES);
        float var = q0 * (1.0f / N_NODES) - mmm * mmm;
        float s = gw[t] * rsqrtf(var + BN_EPS);
        sc[t] = s; sh[t] = gb[t] - mmm * s; w[t] = w2[t];
    }
    __syncthreads();
    int i = blockIdx.x * blockDim.x + t;
    if (i >= N_NODES) return;
    float z = b2[0];
    const float* row = y + (size_t)i * 64;
    #pragma unroll
    for (int c = 0; c < 64; c += 4) {
        float4 v4 = *(const float4*)(row + c);
        float v;
        v = v4.x * sc[c]   + sh[c];   v = v > 0.f ? v : SLOPE * v; z += v * w[c];
        v = v4.y * sc[c+1] + sh[c+1]; v = v > 0.f ? v : SLOPE * v; z += v * w[c+1];
        v = v4.z * sc[c+2] + sh[c+2]; v = v > 0.f ? v : SLOPE * v; z += v * w[c+2];
        v = v4.w * sc[c+3] + sh[c+3]; v = v > 0.f ? v : SLOPE * v; z += v * w[c+3];
    }
    out[i] = 1.f / (1.f + __expf(-z));
}

// ---------------------------------------------------------------------------
extern "C" void kernel_launch(void* const* d_in, const int* in_sizes, int n_in,
                              void* d_out, int out_size, void* d_ws, size_t ws_size,
                              hipStream_t stream) {
    const float* emb_deg = (const float*)d_in[0];
    const float* emb_lab = (const float*)d_in[1];
    const float* wA[3]  = {(const float*)d_in[2],  (const float*)d_in[8],  (const float*)d_in[14]};
    const float* bA[3]  = {(const float*)d_in[3],  (const float*)d_in[9],  (const float*)d_in[15]};
    const float* wB[3]  = {(const float*)d_in[4],  (const float*)d_in[10], (const float*)d_in[16]};
    const float* bB[3]  = {(const float*)d_in[5],  (const float*)d_in[11], (const float*)d_in[17]};
    const float* bnw[3] = {(const float*)d_in[6],  (const float*)d_in[12], (const float*)d_in[18]};
    const float* bnb[3] = {(const float*)d_in[7],  (const float*)d_in[13], (const float*)d_in[19]};
    const float* fc1_w  = (const float*)d_in[20];
    const float* fc1_b  = (const float*)d_in[21];
    const float* fcbn_w = (const float*)d_in[22];
    const float* fcbn_b = (const float*)d_in[23];
    const float* fc2_w  = (const float*)d_in[24];
    const float* fc2_b  = (const float*)d_in[25];
    const int* node_deg = (const int*)d_in[26];
    const int* node_lab = (const int*)d_in[27];
    const int* src = (const int*)d_in[28];
    const int* dst = src + E_EDGES;
    float* out = (float*)d_out;

    // workspace layout (keep ebuf 8B-aligned)
    float* ws   = (float*)d_ws;
    float* ybf  = ws;                                  // N*64 fp32
    float* stat = ybf + (size_t)N_NODES * 64;          // 4 * 32 * 128 floats
    uint_t* x0u = (uint_t*)(stat + 4 * STAT_SHARDS * 128);  // N*64 uints
    uint_t* x1u = x0u + (size_t)N_NODES * 64;          // N*32
    uint_t* x2u = x1u + (size_t)N_NODES * 32;          // N*32
    uint_t* x3u = x2u + (size_t)N_NODES * 32;          // N*32
    int2* ebuf  = (int2*)(x3u + (size_t)N_NODES * 32); // E int2 (8B aligned)
    ushort_t* wbf = (ushort_t*)(ebuf + E_EDGES);       // WTOT bf16
    int* cdeg   = (int*)(wbf + WTOT);                  // N
    int* rowptr = cdeg + N_NODES;
    int* wptr   = rowptr + N_NODES;
    int* ncls   = wptr + N_NODES;
    int* bsum   = ncls + N_NODES;
    int* bofs   = bsum + SCAN_BLOCKS;

    const int RB = (N_NODES + 15) / 16;            // 3125 row-tile blocks
    const int VB = (N_NODES * 16 + 255) / 256;     // 3125 float4 elementwise blocks
    const int HB = (N_NODES * 64 + 255) / 256;     // 12500 build-x0 blocks
    const int EB = (E_EDGES + 255) / 256;          // 3125 edge blocks
    const int NB = (N_NODES + 255) / 256;          // 196 node blocks

    hipMemsetAsync(stat, 0, (size_t)(4 * STAT_SHARDS * 128) * sizeof(float), stream);
    hipMemsetAsync(cdeg, 0, (size_t)N_NODES * sizeof(int), stream);

    k_cvt<<<(WTOT + 255) / 256, 256, 0, stream>>>(wA[0], wB[0], wA[1], wB[1],
                                                  wA[2], wB[2], fc1_w, wbf);
    k_build_x0<<<HB, 256, 0, stream>>>(emb_deg, emb_lab, node_deg, node_lab, x0u, ncls);

    // ---- CSR build
    k_deg<<<EB, 256, 0, stream>>>(dst, cdeg);
    k_scan_a<<<SCAN_BLOCKS, 256, 0, stream>>>(cdeg, bsum);
    k_scan_b<<<1, 64, 0, stream>>>(bsum, bofs);
    k_scan_c<<<SCAN_BLOCKS, 256, 0, stream>>>(cdeg, bofs, rowptr, wptr);
    k_fill<<<EB, 256, 0, stream>>>(src, dst, ncls, wptr, ebuf);

    // ---- 3 GIN layers
    const ushort_t* waOfs[3] = {wbf + OWA0, wbf + OWA1, wbf + OWA2};
    const ushort_t* wbOfs[3] = {wbf + OWB0, wbf + OWB1, wbf + OWB2};
    uint_t* xin[4] = {x0u, x1u, x2u, x3u};
    for (int l = 0; l < 3; ++l) {
        float* st = stat + l * STAT_SHARDS * 128;
        if (l == 0)
            k_mlp<128><<<RB, 256, 0, stream>>>((const ushort_t*)xin[l], rowptr, cdeg,
                ebuf, ncls, emb_deg, emb_lab,
                waOfs[l], bA[l], wbOfs[l], bB[l], ybf, st);
        else
            k_mlp<64><<<RB, 256, 0, stream>>>((const ushort_t*)xin[l], rowptr, cdeg,
                ebuf, ncls, emb_deg, emb_lab,
                waOfs[l], bA[l], wbOfs[l], bB[l], ybf, st);
        k_bn_apply<<<VB, 256, 0, stream>>>(ybf, st, bnw[l], bnb[l], xin[l + 1]);
    }

    float* stf = stat + 3 * STAT_SHARDS * 128;
    k_fc1<<<RB, 256, 0, stream>>>(x0u, x1u, x2u, x3u, wbf + OFC1, fc1_b, ybf, stf);
    k_final<<<NB, 256, 0, stream>>>(ybf, stf, fcbn_w, fcbn_b, fc2_w, fc2_b, out);
}